// Round 1
// baseline (27408.282 us; speedup 1.0000x reference)
//
#include <hip/hip_runtime.h>
#include <hip/hip_bf16.h>

#define NL 4
#define NB 64
#define NT 512
#define NH 1024
#define N3H 3072
#define FSTRIDE 4   // ints per flag slot (16 B padding)

typedef __attribute__((ext_vector_type(8))) short short8;
typedef __attribute__((ext_vector_type(4))) float floatx4;

__device__ __forceinline__ short8 ld8(const __hip_bfloat16* p) {
  return *(const short8*)p;
}

// ---------------- prep kernels ----------------

// w_ih -> bf16 ; w_hh -> bf16 hi (all rows) + bf16 lo (n-gate rows only)
__global__ void conv_w_kernel(const float* __restrict__ w_ih,
                              const float* __restrict__ w_hh,
                              __hip_bfloat16* __restrict__ wih_b,
                              __hip_bfloat16* __restrict__ whh_hi,
                              __hip_bfloat16* __restrict__ whh_lo_n) {
  size_t i = (size_t)blockIdx.x * 256 + threadIdx.x;
  if (i >= (size_t)NL * N3H * NH) return;
  wih_b[i] = __float2bfloat16(w_ih[i]);
  float v = w_hh[i];
  __hip_bfloat16 hi = __float2bfloat16(v);
  whh_hi[i] = hi;
  size_t l = i / ((size_t)N3H * NH);
  size_t rem = i - l * ((size_t)N3H * NH);
  size_t row = rem / NH;
  if (row >= (size_t)2 * NH) {
    size_t k = rem - row * NH;
    whh_lo_n[(l * NH + (row - 2 * NH)) * NH + k] =
        __float2bfloat16(v - __bfloat162float(hi));
  }
}

__global__ void conv_x_kernel(const float* __restrict__ x,
                              __hip_bfloat16* __restrict__ xb) {
  size_t i = (size_t)blockIdx.x * 256 + threadIdx.x;
  if (i >= (size_t)NT * NB * NH) return;
  xb[i] = __float2bfloat16(x[i]);
}

// h0 -> d_out (fp32 master) ; zero the flag array
__global__ void init_out_kernel(const float* __restrict__ h0,
                                float* __restrict__ out,
                                int* __restrict__ flags) {
  size_t i = (size_t)blockIdx.x * 256 + threadIdx.x;
  if (i < (size_t)4 * 64 * FSTRIDE) flags[i] = 0;
  if (i >= (size_t)NL * NB * NH) return;
  out[i] = h0[i];
}

__global__ void init_hbf_kernel(const float* __restrict__ h0_layer,
                                __hip_bfloat16* __restrict__ hb) {
  size_t i = (size_t)blockIdx.x * 256 + threadIdx.x;
  if (i >= (size_t)NB * NH) return;
  hb[i] = __float2bfloat16(h0_layer[i]);
}

// ---------------- gi GEMM: C[M][3072] = A[M][1024] @ W[3072][1024]^T + bih --
__global__ __launch_bounds__(256) void gemm_gi_kernel(
    const __hip_bfloat16* __restrict__ A,
    const __hip_bfloat16* __restrict__ Wb,
    const float* __restrict__ bih,
    float* __restrict__ C) {
  __shared__ short lA[128 * 32];
  __shared__ short lB[128 * 32];
  const int tid = threadIdx.x;
  const int wave = tid >> 6, lane = tid & 63;
  const int l15 = lane & 15, quad = lane >> 4;
  const int m0 = blockIdx.x * 128;
  const int n0 = blockIdx.y * 128;
  const int wm = (wave >> 1) * 64, wn = (wave & 1) * 64;

  const int r1 = tid >> 2, c1 = (tid & 3) * 8;
  const __hip_bfloat16* Arow0 = A + (size_t)(m0 + r1) * NH + c1;
  const __hip_bfloat16* Arow1 = A + (size_t)(m0 + r1 + 64) * NH + c1;
  const __hip_bfloat16* Brow0 = Wb + (size_t)(n0 + r1) * NH + c1;
  const __hip_bfloat16* Brow1 = Wb + (size_t)(n0 + r1 + 64) * NH + c1;

  floatx4 z4 = {0.f, 0.f, 0.f, 0.f};
  floatx4 acc[4][4];
#pragma unroll
  for (int mi = 0; mi < 4; ++mi)
#pragma unroll
    for (int ni = 0; ni < 4; ++ni) acc[mi][ni] = z4;

  for (int kt = 0; kt < 32; ++kt) {
    const int ko = kt * 32;
    short8 a0 = ld8(Arow0 + ko), a1 = ld8(Arow1 + ko);
    short8 b0 = ld8(Brow0 + ko), b1 = ld8(Brow1 + ko);
    __syncthreads();
    *(short8*)(lA + tid * 8) = a0;
    *(short8*)(lA + (tid + 256) * 8) = a1;
    *(short8*)(lB + tid * 8) = b0;
    *(short8*)(lB + (tid + 256) * 8) = b1;
    __syncthreads();
    short8 af[4], bf[4];
#pragma unroll
    for (int mi = 0; mi < 4; ++mi)
      af[mi] = *(short8*)(lA + (wm + mi * 16 + l15) * 32 + quad * 8);
#pragma unroll
    for (int ni = 0; ni < 4; ++ni)
      bf[ni] = *(short8*)(lB + (wn + ni * 16 + l15) * 32 + quad * 8);
#pragma unroll
    for (int mi = 0; mi < 4; ++mi)
#pragma unroll
      for (int ni = 0; ni < 4; ++ni)
        acc[mi][ni] =
            __builtin_amdgcn_mfma_f32_16x16x32_bf16(af[mi], bf[ni], acc[mi][ni], 0, 0, 0);
  }

  const int crow = m0 + wm + quad * 4;
#pragma unroll
  for (int ni = 0; ni < 4; ++ni) {
    const int col = n0 + wn + ni * 16 + l15;
    const float bias = bih[col];
#pragma unroll
    for (int mi = 0; mi < 4; ++mi)
#pragma unroll
      for (int r = 0; r < 4; ++r)
        C[(size_t)(crow + mi * 16 + r) * N3H + col] = acc[mi][ni][r] + bias;
  }
}

// ---------------- recurrent chunk kernel ----------------
// Fence-free cross-block sync: h exchanged via sc0/sc1 write-through stores +
// cache-bypass loads (always-fresh at the LLC coherence point). Flags are
// RELAXED agent atomics -> no buffer_inv / buffer_wbl2 cache maintenance,
// L2 stays warm with the streamed r/z weights across all steps.
__global__ __launch_bounds__(64) void gru_persist_kernel(
    const __hip_bfloat16* __restrict__ whh_hi_l,  // [3072][1024]
    const __hip_bfloat16* __restrict__ whh_lo_l,  // [1024][1024] n-gate lo
    const float* __restrict__ gi_c,               // [TC][64][3072]
    const float* __restrict__ bhh_l,              // [3072]
    __hip_bfloat16* hbuf,                         // [2][64][1024] ping-pong
    __hip_bfloat16* seq_out,                      // [TC][64][1024] or null
    float* hfp,                                   // d_out + l*64*1024
    int* flags,                                   // [4*64*FSTRIDE]
    int s0, int nsteps) {
  const int lane = threadIdx.x;
  const int w = blockIdx.x >> 6;
  const int g = blockIdx.x & 63;
  const int l15 = lane & 15, quad = lane >> 4;
  const int u = g * 16 + l15;

  __shared__ short lds[32768];  // [2][32 kc][64 lane][8 bf16] = 64 KB

  // stage n-gate frags (hi+lo) in fragment order: conflict-free ds_read_b128
  {
    const __hip_bfloat16* srch = whh_hi_l + ((size_t)(2 * NH) + u) * NH + quad * 8;
    const __hip_bfloat16* srcl = whh_lo_l + (size_t)u * NH + quad * 8;
    short* dst = lds + lane * 8;
#pragma unroll 4
    for (int kc = 0; kc < 32; ++kc) {
      *(short8*)(dst + kc * 512) = ld8(srch + kc * 32);
      *(short8*)(dst + 16384 + kc * 512) = ld8(srcl + kc * 32);
    }
  }
  __syncthreads();

  const int bb = w * 16 + quad * 4;  // first batch row of this lane's acc
  float hreg[4];
#pragma unroll
  for (int r = 0; r < 4; ++r) hreg[r] = hfp[(size_t)(bb + r) * NH + u];

  const float bhr = bhh_l[u], bhz = bhh_l[NH + u], bhn = bhh_l[2 * NH + u];
  const __hip_bfloat16* wr = whh_hi_l + (size_t)u * NH + quad * 8;
  const __hip_bfloat16* wz = whh_hi_l + ((size_t)NH + u) * NH + quad * 8;

  int* myflag = flags + (w * 64 + lane) * FSTRIDE;  // producer this lane watches
  int* outflag = flags + (w * 64 + g) * FSTRIDE;    // this block's flag
  __hip_bfloat16* hb0 = hbuf;
  __hip_bfloat16* hb1 = hbuf + NB * NH;

  for (int s = s0; s < s0 + nsteps; ++s) {
    const int tc = s - s0;
    // gi prefetch (independent of the flag -> can be in flight during spin)
    const float* gp = gi_c + ((size_t)tc * NB + bb) * N3H + u;
    float gi_r[4], gi_z[4], gi_n[4];
#pragma unroll
    for (int r = 0; r < 4; ++r) {
      gi_r[r] = gp[(size_t)r * N3H];
      gi_z[r] = gp[(size_t)r * N3H + NH];
      gi_n[r] = gp[(size_t)r * N3H + 2 * NH];
    }

    // wait until all 64 producers of this batch-group published state s
    while (__hip_atomic_load(myflag, __ATOMIC_RELAXED, __HIP_MEMORY_SCOPE_AGENT) < s)
      __builtin_amdgcn_s_sleep(1);

    // h fragments: cache-bypass loads (sc0 sc1 -> read the LLC, never stale)
    const __hip_bfloat16* hbase =
        ((s & 1) ? hb1 : hb0) + (size_t)(w * 16 + l15) * NH + quad * 8;
    short8 hf[32];
#pragma unroll
    for (int kc = 0; kc < 32; ++kc)
      asm volatile("global_load_dwordx4 %0, %1, off sc0 sc1"
                   : "=v"(hf[kc]) : "v"(hbase + kc * 32));
    // tie the loaded regs to a vmcnt(0) so no MFMA consumes them early
#pragma unroll
    for (int g8 = 0; g8 < 32; g8 += 8)
      asm volatile("s_waitcnt vmcnt(0)"
                   : "+v"(hf[g8]), "+v"(hf[g8 + 1]), "+v"(hf[g8 + 2]),
                     "+v"(hf[g8 + 3]), "+v"(hf[g8 + 4]), "+v"(hf[g8 + 5]),
                     "+v"(hf[g8 + 6]), "+v"(hf[g8 + 7])
                   :: "memory");

    floatx4 accr = {0.f, 0.f, 0.f, 0.f}, accz = accr, accnh = accr, accnl = accr;
#pragma unroll 8
    for (int kc = 0; kc < 32; ++kc) {
      short8 ah = hf[kc];
      short8 brf = ld8(wr + kc * 32);
      short8 bzf = ld8(wz + kc * 32);
      short8 bnh = *(short8*)(lds + lane * 8 + kc * 512);
      short8 bnl = *(short8*)(lds + 16384 + lane * 8 + kc * 512);
      accr = __builtin_amdgcn_mfma_f32_16x16x32_bf16(ah, brf, accr, 0, 0, 0);
      accz = __builtin_amdgcn_mfma_f32_16x16x32_bf16(ah, bzf, accz, 0, 0, 0);
      accnh = __builtin_amdgcn_mfma_f32_16x16x32_bf16(ah, bnh, accnh, 0, 0, 0);
      accnl = __builtin_amdgcn_mfma_f32_16x16x32_bf16(ah, bnl, accnl, 0, 0, 0);
    }

    __hip_bfloat16* hout = (s & 1) ? hb0 : hb1;
#pragma unroll
    for (int r = 0; r < 4; ++r) {
      float ghr = accr[r] + bhr;
      float ghz = accz[r] + bhz;
      float ghn = accnh[r] + accnl[r] + bhn;
      float rr = 1.f / (1.f + __expf(-(gi_r[r] + ghr)));
      float zz = 1.f / (1.f + __expf(-(gi_z[r] + ghz)));
      float xt = gi_n[r] + rr * ghn;
      xt = fminf(fmaxf(xt, -15.f), 15.f);
      float e2 = __expf(2.f * xt);
      float nn = (e2 - 1.f) / (e2 + 1.f);
      float hn = (1.f - zz) * nn + zz * hreg[r];
      hreg[r] = hn;
      __hip_bfloat16 hb16 = __float2bfloat16(hn);
      size_t idx = (size_t)(bb + r) * NH + u;
      // write-through to the LLC (no dirty L2 line -> vmcnt(0) is a full release)
      unsigned int v32 = (unsigned int)__builtin_bit_cast(unsigned short, hb16);
      asm volatile("global_store_short %0, %1, off sc0 sc1"
                   :: "v"(hout + idx), "v"(v32) : "memory");
      if (seq_out) seq_out[(size_t)tc * (NB * NH) + idx] = hb16;
    }
    asm volatile("s_waitcnt vmcnt(0)" ::: "memory");  // h visible at LLC
    if (lane == 0)
      __hip_atomic_store(outflag, s + 1, __ATOMIC_RELAXED, __HIP_MEMORY_SCOPE_AGENT);
  }

#pragma unroll
  for (int r = 0; r < 4; ++r) hfp[(size_t)(bb + r) * NH + u] = hreg[r];
}

// ---------------- launch ----------------
extern "C" void kernel_launch(void* const* d_in, const int* in_sizes, int n_in,
                              void* d_out, int out_size, void* d_ws, size_t ws_size,
                              hipStream_t stream) {
  const float* x = (const float*)d_in[0];
  const float* h0 = (const float*)d_in[1];
  const float* w_ih = (const float*)d_in[2];
  const float* w_hh = (const float*)d_in[3];
  const float* b_ih = (const float*)d_in[4];
  const float* b_hh = (const float*)d_in[5];
  float* out = (float*)d_out;
  (void)in_sizes; (void)n_in; (void)out_size;

  char* ws = (char*)d_ws;
  size_t off = 0;
  const size_t wsz = (size_t)NL * N3H * NH * 2;  // 25.2 MB
  const size_t lsz = (size_t)NL * NH * NH * 2;   // 8.4 MB
  const size_t ssz = (size_t)NT * NB * NH * 2;   // 67.1 MB
  __hip_bfloat16* wih_b = (__hip_bfloat16*)(ws + off); off += wsz;
  __hip_bfloat16* whh_hi = (__hip_bfloat16*)(ws + off); off += wsz;
  __hip_bfloat16* whh_lo = (__hip_bfloat16*)(ws + off); off += lsz;
  __hip_bfloat16* seqA = (__hip_bfloat16*)(ws + off); off += ssz;
  __hip_bfloat16* seqB = (__hip_bfloat16*)(ws + off); off += ssz;
  __hip_bfloat16* hbuf = (__hip_bfloat16*)(ws + off); off += (size_t)2 * NB * NH * 2;
  int* flags = (int*)(ws + off); off += (size_t)4 * 64 * FSTRIDE * 4;
  off = (off + 255) & ~(size_t)255;
  float* gi_buf = (float*)(ws + off);

  // pick largest chunk length TC (divides 512) whose fp32 gi buffer fits
  long long avail = (long long)ws_size - (long long)off;
  int TC = 256;
  while (TC > 2 && (long long)TC * NB * N3H * 4 > avail) TC >>= 1;

  {
    size_t n = (size_t)NL * N3H * NH;
    conv_w_kernel<<<dim3((n + 255) / 256), dim3(256), 0, stream>>>(
        w_ih, w_hh, wih_b, whh_hi, whh_lo);
  }
  {
    size_t n = (size_t)NT * NB * NH;
    conv_x_kernel<<<dim3((n + 255) / 256), dim3(256), 0, stream>>>(x, seqA);
  }
  {
    size_t n = (size_t)NL * NB * NH;
    init_out_kernel<<<dim3((n + 255) / 256), dim3(256), 0, stream>>>(h0, out, flags);
  }

  const size_t bh = (size_t)NB * NH;
  const int nchunks = NT / TC;
  for (int l = 0; l < NL; ++l) {
    init_hbf_kernel<<<dim3((bh + 255) / 256), dim3(256), 0, stream>>>(
        h0 + (size_t)l * bh, hbuf);
    const __hip_bfloat16* cur = (l & 1) ? seqB : seqA;
    __hip_bfloat16* nxt = (l == NL - 1) ? (__hip_bfloat16*)nullptr
                                        : ((l & 1) ? seqA : seqB);
    const __hip_bfloat16* wih_l = wih_b + (size_t)l * N3H * NH;
    const __hip_bfloat16* whha_l = whh_hi + (size_t)l * N3H * NH;
    const __hip_bfloat16* whhb_l = whh_lo + (size_t)l * NH * NH;
    const float* bih_l = b_ih + (size_t)l * N3H;
    const float* bhh_l = b_hh + (size_t)l * N3H;
    float* hfp_l = out + (size_t)l * bh;
    for (int c = 0; c < nchunks; ++c) {
      const __hip_bfloat16* Ac = cur + (size_t)c * TC * bh;
      gemm_gi_kernel<<<dim3(TC * NB / 128, N3H / 128), dim3(256), 0, stream>>>(
          Ac, wih_l, bih_l, gi_buf);
      __hip_bfloat16* so = nxt ? nxt + (size_t)c * TC * bh : (__hip_bfloat16*)nullptr;
      gru_persist_kernel<<<dim3(256), dim3(64), 0, stream>>>(
          whha_l, whhb_l, gi_buf, bhh_l, hbuf, so, hfp_l, flags,
          l * NT + c * TC, TC);
    }
  }
}

// Round 2
// 15441.226 us; speedup vs baseline: 1.7750x; 1.7750x over previous
//
#include <hip/hip_runtime.h>
#include <hip/hip_bf16.h>

#define NL 4
#define NB 64
#define NT 512
#define NH 1024
#define N3H 3072
#define BH 65536            // NB*NH
#define HS_SLOTS 513        // h0 + 512 steps
#define FSTRIDE 4           // ints per flag slot (16 B padding)

typedef __attribute__((ext_vector_type(8))) short short8;
typedef __attribute__((ext_vector_type(4))) float floatx4;

__device__ __forceinline__ short8 ld8(const __hip_bfloat16* p) {
  return *(const short8*)p;
}

// ---------------- prep kernels (shared) ----------------

// w_ih -> bf16 ; w_hh -> bf16 hi (all rows) + bf16 lo (n-gate rows only)
__global__ void conv_w_kernel(const float* __restrict__ w_ih,
                              const float* __restrict__ w_hh,
                              __hip_bfloat16* __restrict__ wih_b,
                              __hip_bfloat16* __restrict__ whh_hi,
                              __hip_bfloat16* __restrict__ whh_lo_n) {
  size_t i = (size_t)blockIdx.x * 256 + threadIdx.x;
  if (i >= (size_t)NL * N3H * NH) return;
  wih_b[i] = __float2bfloat16(w_ih[i]);
  float v = w_hh[i];
  __hip_bfloat16 hi = __float2bfloat16(v);
  whh_hi[i] = hi;
  size_t l = i / ((size_t)N3H * NH);
  size_t rem = i - l * ((size_t)N3H * NH);
  size_t row = rem / NH;
  if (row >= (size_t)2 * NH) {
    size_t k = rem - row * NH;
    whh_lo_n[(l * NH + (row - 2 * NH)) * NH + k] =
        __float2bfloat16(v - __bfloat162float(hi));
  }
}

__global__ void conv_x_kernel(const float* __restrict__ x,
                              __hip_bfloat16* __restrict__ xb) {
  size_t i = (size_t)blockIdx.x * 256 + threadIdx.x;
  if (i >= (size_t)NT * NB * NH) return;
  xb[i] = __float2bfloat16(x[i]);
}

// ---------------- wavefront-path init ----------------
// h0 -> out (fp32 master) and hseq slot 0 (bf16); flags: layers 0-3 zero,
// dummy group 4 (layer 0's "upstream") preset huge so its wait never blocks.
__global__ void init_wave_kernel(const float* __restrict__ h0,
                                 float* __restrict__ out,
                                 __hip_bfloat16* __restrict__ hseq,
                                 int* __restrict__ flags) {
  size_t i = (size_t)blockIdx.x * 256 + threadIdx.x;
  if (i < (size_t)5 * 64 * FSTRIDE)
    flags[i] = (i < (size_t)4 * 64 * FSTRIDE) ? 0 : 0x3fffffff;
  if (i >= (size_t)NL * NB * NH) return;
  out[i] = h0[i];
  size_t l = i >> 16;          // / BH
  size_t j = i & (BH - 1);
  hseq[l * (size_t)HS_SLOTS * BH + j] = __float2bfloat16(h0[i]);
}

// ---------------- layer-wavefront persistent kernel ----------------
// Grid: 256 blocks x 128 threads. Block (l,g) owns u-cols [g*16,g*16+16) of
// layer l for ALL 64 batch rows; wave wv owns rows [wv*32, wv*32+32).
// All 4 layers run concurrently: critical path = 512+3 exchange rounds
// instead of 4*512. gi (= x @ W_ih^T) is computed in-kernel from the
// upstream layer's h (bf16 MFMA, fp32 acc — numerically identical to the
// old precomputed GEMM). h is exchanged via hseq: one UNIQUE slot per tick,
// written with sc0/sc1 write-through (LLC-visible before the flag), read
// with plain cached loads (a never-before-touched address cannot be stale;
// dispatch-start acquire invalidates caches between graph replays).
__global__ __launch_bounds__(128, 1) void gru_wave_kernel(
    const __hip_bfloat16* __restrict__ whh_hi,  // [L][3072][1024]
    const __hip_bfloat16* __restrict__ whh_lo,  // [L][1024][1024] n-gate lo
    const __hip_bfloat16* __restrict__ wih,     // [L][3072][1024]
    const __hip_bfloat16* __restrict__ xb,      // [512][64][1024]
    const float* __restrict__ b_ih,             // [L][3072]
    const float* __restrict__ b_hh,             // [L][3072]
    __hip_bfloat16* hseq,                       // [L][513][64][1024]
    float* __restrict__ out,                    // [L][64][1024]
    int* flags) {                               // [5][64][FSTRIDE]
  const int tid = threadIdx.x;
  const int wv = tid >> 6, lane = tid & 63;
  const int l = blockIdx.x >> 6, g = blockIdx.x & 63;
  const int l15 = lane & 15, quad = lane >> 4;
  const int u = g * 16 + l15;

  __shared__ short lds[32768];  // [2][32 kc][64 lane][8 bf16] = 64 KB

  // stage n-gate frags: wave0 -> hi, wave1 -> lo (fragment order, same
  // conflict-free layout as the proven persistent kernel)
  {
    const __hip_bfloat16* src =
        (wv == 0) ? whh_hi + (((size_t)l * N3H) + 2 * NH + u) * NH + quad * 8
                  : whh_lo + (((size_t)l * NH) + u) * NH + quad * 8;
    short* dst = lds + wv * 16384 + lane * 8;
#pragma unroll 4
    for (int kc = 0; kc < 32; ++kc)
      *(short8*)(dst + kc * 512) = ld8(src + kc * 32);
  }
  __syncthreads();

  const size_t l3h = (size_t)l * N3H;
  const __hip_bfloat16* wr = whh_hi + (l3h + u) * NH + quad * 8;
  const __hip_bfloat16* wz = whh_hi + (l3h + NH + u) * NH + quad * 8;
  const __hip_bfloat16* vr = wih + (l3h + u) * NH + quad * 8;
  const __hip_bfloat16* vz = wih + (l3h + NH + u) * NH + quad * 8;
  const __hip_bfloat16* vn = wih + (l3h + 2 * NH + u) * NH + quad * 8;
  const float bir = b_ih[l3h + u], biz = b_ih[l3h + NH + u],
              bin = b_ih[l3h + 2 * NH + u];
  const float bhr = b_hh[l3h + u], bhz = b_hh[l3h + NH + u],
              bhn = b_hh[l3h + 2 * NH + u];

  __hip_bfloat16* hs_l = hseq + (size_t)l * HS_SLOTS * BH;
  const __hip_bfloat16* upbase =
      l ? hseq + (size_t)(l - 1) * HS_SLOTS * BH : xb;
  const int upoff = l ? 1 : 0;  // l>0 reads upstream slot t+1 (h_{l-1}(t))

  const int row0 = wv * 32 + quad * 4;           // + mi*16 + r
  const size_t arow = (size_t)(wv * 32 + l15) * NH + quad * 8;  // A-frag base

  // fp32 master copy of this thread's 8 output elements
  float hreg[8];
#pragma unroll
  for (int mi = 0; mi < 2; ++mi)
#pragma unroll
    for (int r = 0; r < 4; ++r)
      hreg[mi * 4 + r] =
          out[(size_t)l * BH + (size_t)(row0 + mi * 16 + r) * NH + u];

  const int* fo = flags + (l * 64 + lane) * FSTRIDE;          // own layer
  const int* fu = flags + ((l ? (l - 1) : 4) * 64 + lane) * FSTRIDE;  // upstream
  int* fmine = flags + (l * 64 + g) * FSTRIDE;

#pragma unroll 1
  for (int t = 0; t < NT; ++t) {
    // wait: own layer published h(t-1) (flag >= t), upstream published h_up(t)
    while (__hip_atomic_load(fo, __ATOMIC_RELAXED, __HIP_MEMORY_SCOPE_AGENT) < t)
      __builtin_amdgcn_s_sleep(1);
    while (__hip_atomic_load(fu, __ATOMIC_RELAXED, __HIP_MEMORY_SCOPE_AGENT) < t + 1)
      __builtin_amdgcn_s_sleep(1);
    // forbid hoisting any h load above the spins
    __builtin_amdgcn_sched_barrier(0);
    asm volatile("" ::: "memory");

    const __hip_bfloat16* ob = hs_l + (size_t)t * BH + arow;
    const __hip_bfloat16* ub = upbase + (size_t)(t + upoff) * BH + arow;

    floatx4 z4 = {0.f, 0.f, 0.f, 0.f};
    floatx4 ar[2], az[2], anh[2], anl[2], gr[2], gz[2], gn[2];
#pragma unroll
    for (int mi = 0; mi < 2; ++mi) {
      ar[mi] = z4; az[mi] = z4; anh[mi] = z4; anl[mi] = z4;
      gr[mi] = z4; gz[mi] = z4; gn[mi] = z4;
    }

#pragma unroll 4
    for (int kc = 0; kc < 32; ++kc) {
      short8 ho[2], hu[2];
      ho[0] = ld8(ob + kc * 32);
      ho[1] = ld8(ob + (size_t)16 * NH + kc * 32);
      hu[0] = ld8(ub + kc * 32);
      hu[1] = ld8(ub + (size_t)16 * NH + kc * 32);
      short8 brf = ld8(wr + kc * 32);
      short8 bzf = ld8(wz + kc * 32);
      short8 vrf = ld8(vr + kc * 32);
      short8 vzf = ld8(vz + kc * 32);
      short8 vnf = ld8(vn + kc * 32);
      short8 bnh = *(short8*)(lds + lane * 8 + kc * 512);
      short8 bnl = *(short8*)(lds + 16384 + lane * 8 + kc * 512);
#pragma unroll
      for (int mi = 0; mi < 2; ++mi) {
        ar[mi] = __builtin_amdgcn_mfma_f32_16x16x32_bf16(ho[mi], brf, ar[mi], 0, 0, 0);
        az[mi] = __builtin_amdgcn_mfma_f32_16x16x32_bf16(ho[mi], bzf, az[mi], 0, 0, 0);
        anh[mi] = __builtin_amdgcn_mfma_f32_16x16x32_bf16(ho[mi], bnh, anh[mi], 0, 0, 0);
        anl[mi] = __builtin_amdgcn_mfma_f32_16x16x32_bf16(ho[mi], bnl, anl[mi], 0, 0, 0);
        gr[mi] = __builtin_amdgcn_mfma_f32_16x16x32_bf16(hu[mi], vrf, gr[mi], 0, 0, 0);
        gz[mi] = __builtin_amdgcn_mfma_f32_16x16x32_bf16(hu[mi], vzf, gz[mi], 0, 0, 0);
        gn[mi] = __builtin_amdgcn_mfma_f32_16x16x32_bf16(hu[mi], vnf, gn[mi], 0, 0, 0);
      }
    }

    __hip_bfloat16* hw = hs_l + (size_t)(t + 1) * BH;
#pragma unroll
    for (int mi = 0; mi < 2; ++mi) {
#pragma unroll
      for (int r = 0; r < 4; ++r) {
        float ghr = ar[mi][r] + bhr;
        float ghz = az[mi][r] + bhz;
        float ghn = anh[mi][r] + anl[mi][r] + bhn;
        float gir = gr[mi][r] + bir;
        float giz = gz[mi][r] + biz;
        float gin = gn[mi][r] + bin;
        float rr = 1.f / (1.f + __expf(-(gir + ghr)));
        float zz = 1.f / (1.f + __expf(-(giz + ghz)));
        float xt = gin + rr * ghn;
        xt = fminf(fmaxf(xt, -15.f), 15.f);
        float e2 = __expf(2.f * xt);
        float nn = (e2 - 1.f) / (e2 + 1.f);
        float hn = (1.f - zz) * nn + zz * hreg[mi * 4 + r];
        hreg[mi * 4 + r] = hn;
        __hip_bfloat16 hb16 = __float2bfloat16(hn);
        unsigned int v32 = (unsigned int)__builtin_bit_cast(unsigned short, hb16);
        // write-through to the LLC so vmcnt(0) is a full release
        asm volatile("global_store_short %0, %1, off sc0 sc1"
                     :: "v"(hw + (size_t)(row0 + mi * 16 + r) * NH + u),
                        "v"(v32) : "memory");
      }
    }
    asm volatile("s_waitcnt vmcnt(0)" ::: "memory");  // h visible at LLC
    __syncthreads();                                  // both waves done
    if (tid == 0)
      __hip_atomic_store(fmine, t + 1, __ATOMIC_RELAXED, __HIP_MEMORY_SCOPE_AGENT);
  }

#pragma unroll
  for (int mi = 0; mi < 2; ++mi)
#pragma unroll
    for (int r = 0; r < 4; ++r)
      out[(size_t)l * BH + (size_t)(row0 + mi * 16 + r) * NH + u] =
          hreg[mi * 4 + r];
}

// ================= fallback path (previous verified kernel) =================

__global__ void init_out_kernel(const float* __restrict__ h0,
                                float* __restrict__ out,
                                int* __restrict__ flags) {
  size_t i = (size_t)blockIdx.x * 256 + threadIdx.x;
  if (i < (size_t)4 * 64 * FSTRIDE) flags[i] = 0;
  if (i >= (size_t)NL * NB * NH) return;
  out[i] = h0[i];
}

__global__ void init_hbf_kernel(const float* __restrict__ h0_layer,
                                __hip_bfloat16* __restrict__ hb) {
  size_t i = (size_t)blockIdx.x * 256 + threadIdx.x;
  if (i >= (size_t)NB * NH) return;
  hb[i] = __float2bfloat16(h0_layer[i]);
}

__global__ __launch_bounds__(256) void gemm_gi_kernel(
    const __hip_bfloat16* __restrict__ A,
    const __hip_bfloat16* __restrict__ Wb,
    const float* __restrict__ bih,
    float* __restrict__ C) {
  __shared__ short lA[128 * 32];
  __shared__ short lB[128 * 32];
  const int tid = threadIdx.x;
  const int wave = tid >> 6, lane = tid & 63;
  const int l15 = lane & 15, quad = lane >> 4;
  const int m0 = blockIdx.x * 128;
  const int n0 = blockIdx.y * 128;
  const int wm = (wave >> 1) * 64, wn = (wave & 1) * 64;

  const int r1 = tid >> 2, c1 = (tid & 3) * 8;
  const __hip_bfloat16* Arow0 = A + (size_t)(m0 + r1) * NH + c1;
  const __hip_bfloat16* Arow1 = A + (size_t)(m0 + r1 + 64) * NH + c1;
  const __hip_bfloat16* Brow0 = Wb + (size_t)(n0 + r1) * NH + c1;
  const __hip_bfloat16* Brow1 = Wb + (size_t)(n0 + r1 + 64) * NH + c1;

  floatx4 z4 = {0.f, 0.f, 0.f, 0.f};
  floatx4 acc[4][4];
#pragma unroll
  for (int mi = 0; mi < 4; ++mi)
#pragma unroll
    for (int ni = 0; ni < 4; ++ni) acc[mi][ni] = z4;

  for (int kt = 0; kt < 32; ++kt) {
    const int ko = kt * 32;
    short8 a0 = ld8(Arow0 + ko), a1 = ld8(Arow1 + ko);
    short8 b0 = ld8(Brow0 + ko), b1 = ld8(Brow1 + ko);
    __syncthreads();
    *(short8*)(lA + tid * 8) = a0;
    *(short8*)(lA + (tid + 256) * 8) = a1;
    *(short8*)(lB + tid * 8) = b0;
    *(short8*)(lB + (tid + 256) * 8) = b1;
    __syncthreads();
    short8 af[4], bf[4];
#pragma unroll
    for (int mi = 0; mi < 4; ++mi)
      af[mi] = *(short8*)(lA + (wm + mi * 16 + l15) * 32 + quad * 8);
#pragma unroll
    for (int ni = 0; ni < 4; ++ni)
      bf[ni] = *(short8*)(lB + (wn + ni * 16 + l15) * 32 + quad * 8);
#pragma unroll
    for (int mi = 0; mi < 4; ++mi)
#pragma unroll
      for (int ni = 0; ni < 4; ++ni)
        acc[mi][ni] =
            __builtin_amdgcn_mfma_f32_16x16x32_bf16(af[mi], bf[ni], acc[mi][ni], 0, 0, 0);
  }

  const int crow = m0 + wm + quad * 4;
#pragma unroll
  for (int ni = 0; ni < 4; ++ni) {
    const int col = n0 + wn + ni * 16 + l15;
    const float bias = bih[col];
#pragma unroll
    for (int mi = 0; mi < 4; ++mi)
#pragma unroll
      for (int r = 0; r < 4; ++r)
        C[(size_t)(crow + mi * 16 + r) * N3H + col] = acc[mi][ni][r] + bias;
  }
}

__global__ __launch_bounds__(64) void gru_persist_kernel(
    const __hip_bfloat16* __restrict__ whh_hi_l,
    const __hip_bfloat16* __restrict__ whh_lo_l,
    const float* __restrict__ gi_c,
    const float* __restrict__ bhh_l,
    __hip_bfloat16* hbuf,
    __hip_bfloat16* seq_out,
    float* hfp,
    int* flags,
    int s0, int nsteps) {
  const int lane = threadIdx.x;
  const int w = blockIdx.x >> 6;
  const int g = blockIdx.x & 63;
  const int l15 = lane & 15, quad = lane >> 4;
  const int u = g * 16 + l15;

  __shared__ short lds[32768];

  {
    const __hip_bfloat16* srch = whh_hi_l + ((size_t)(2 * NH) + u) * NH + quad * 8;
    const __hip_bfloat16* srcl = whh_lo_l + (size_t)u * NH + quad * 8;
    short* dst = lds + lane * 8;
#pragma unroll 4
    for (int kc = 0; kc < 32; ++kc) {
      *(short8*)(dst + kc * 512) = ld8(srch + kc * 32);
      *(short8*)(dst + 16384 + kc * 512) = ld8(srcl + kc * 32);
    }
  }
  __syncthreads();

  const int bb = w * 16 + quad * 4;
  float hreg[4];
#pragma unroll
  for (int r = 0; r < 4; ++r) hreg[r] = hfp[(size_t)(bb + r) * NH + u];

  const float bhr = bhh_l[u], bhz = bhh_l[NH + u], bhn = bhh_l[2 * NH + u];
  const __hip_bfloat16* wr = whh_hi_l + (size_t)u * NH + quad * 8;
  const __hip_bfloat16* wz = whh_hi_l + ((size_t)NH + u) * NH + quad * 8;

  int* myflag = flags + (w * 64 + lane) * FSTRIDE;
  int* outflag = flags + (w * 64 + g) * FSTRIDE;
  __hip_bfloat16* hb0 = hbuf;
  __hip_bfloat16* hb1 = hbuf + NB * NH;

  for (int s = s0; s < s0 + nsteps; ++s) {
    const int tc = s - s0;
    const float* gp = gi_c + ((size_t)tc * NB + bb) * N3H + u;
    float gi_r[4], gi_z[4], gi_n[4];
#pragma unroll
    for (int r = 0; r < 4; ++r) {
      gi_r[r] = gp[(size_t)r * N3H];
      gi_z[r] = gp[(size_t)r * N3H + NH];
      gi_n[r] = gp[(size_t)r * N3H + 2 * NH];
    }

    while (__hip_atomic_load(myflag, __ATOMIC_RELAXED, __HIP_MEMORY_SCOPE_AGENT) < s)
      __builtin_amdgcn_s_sleep(1);

    const __hip_bfloat16* hbase =
        ((s & 1) ? hb1 : hb0) + (size_t)(w * 16 + l15) * NH + quad * 8;
    short8 hf[32];
#pragma unroll
    for (int kc = 0; kc < 32; ++kc)
      asm volatile("global_load_dwordx4 %0, %1, off sc0 sc1"
                   : "=v"(hf[kc]) : "v"(hbase + kc * 32));
#pragma unroll
    for (int g8 = 0; g8 < 32; g8 += 8)
      asm volatile("s_waitcnt vmcnt(0)"
                   : "+v"(hf[g8]), "+v"(hf[g8 + 1]), "+v"(hf[g8 + 2]),
                     "+v"(hf[g8 + 3]), "+v"(hf[g8 + 4]), "+v"(hf[g8 + 5]),
                     "+v"(hf[g8 + 6]), "+v"(hf[g8 + 7])
                   :: "memory");

    floatx4 accr = {0.f, 0.f, 0.f, 0.f}, accz = accr, accnh = accr, accnl = accr;
#pragma unroll 8
    for (int kc = 0; kc < 32; ++kc) {
      short8 ah = hf[kc];
      short8 brf = ld8(wr + kc * 32);
      short8 bzf = ld8(wz + kc * 32);
      short8 bnh = *(short8*)(lds + lane * 8 + kc * 512);
      short8 bnl = *(short8*)(lds + 16384 + lane * 8 + kc * 512);
      accr = __builtin_amdgcn_mfma_f32_16x16x32_bf16(ah, brf, accr, 0, 0, 0);
      accz = __builtin_amdgcn_mfma_f32_16x16x32_bf16(ah, bzf, accz, 0, 0, 0);
      accnh = __builtin_amdgcn_mfma_f32_16x16x32_bf16(ah, bnh, accnh, 0, 0, 0);
      accnl = __builtin_amdgcn_mfma_f32_16x16x32_bf16(ah, bnl, accnl, 0, 0, 0);
    }

    __hip_bfloat16* hout = (s & 1) ? hb0 : hb1;
#pragma unroll
    for (int r = 0; r < 4; ++r) {
      float ghr = accr[r] + bhr;
      float ghz = accz[r] + bhz;
      float ghn = accnh[r] + accnl[r] + bhn;
      float rr = 1.f / (1.f + __expf(-(gi_r[r] + ghr)));
      float zz = 1.f / (1.f + __expf(-(gi_z[r] + ghz)));
      float xt = gi_n[r] + rr * ghn;
      xt = fminf(fmaxf(xt, -15.f), 15.f);
      float e2 = __expf(2.f * xt);
      float nn = (e2 - 1.f) / (e2 + 1.f);
      float hn = (1.f - zz) * nn + zz * hreg[r];
      hreg[r] = hn;
      __hip_bfloat16 hb16 = __float2bfloat16(hn);
      size_t idx = (size_t)(bb + r) * NH + u;
      unsigned int v32 = (unsigned int)__builtin_bit_cast(unsigned short, hb16);
      asm volatile("global_store_short %0, %1, off sc0 sc1"
                   :: "v"(hout + idx), "v"(v32) : "memory");
      if (seq_out) seq_out[(size_t)tc * (NB * NH) + idx] = hb16;
    }
    asm volatile("s_waitcnt vmcnt(0)" ::: "memory");
    if (lane == 0)
      __hip_atomic_store(outflag, s + 1, __ATOMIC_RELAXED, __HIP_MEMORY_SCOPE_AGENT);
  }

#pragma unroll
  for (int r = 0; r < 4; ++r) hfp[(size_t)(bb + r) * NH + u] = hreg[r];
}

// ---------------- launch ----------------
extern "C" void kernel_launch(void* const* d_in, const int* in_sizes, int n_in,
                              void* d_out, int out_size, void* d_ws, size_t ws_size,
                              hipStream_t stream) {
  const float* x = (const float*)d_in[0];
  const float* h0 = (const float*)d_in[1];
  const float* w_ih = (const float*)d_in[2];
  const float* w_hh = (const float*)d_in[3];
  const float* b_ih = (const float*)d_in[4];
  const float* b_hh = (const float*)d_in[5];
  float* out = (float*)d_out;
  (void)in_sizes; (void)n_in; (void)out_size;

  char* ws = (char*)d_ws;
  const size_t wsz = (size_t)NL * N3H * NH * 2;   // 25.2 MB
  const size_t lsz = (size_t)NL * NH * NH * 2;    // 8.4 MB
  const size_t xsz = (size_t)NT * NB * NH * 2;    // 67.1 MB
  const size_t hssz = (size_t)NL * HS_SLOTS * BH * 2;  // 269.0 MB
  const size_t fsz = (size_t)5 * 64 * FSTRIDE * 4;
  const size_t need_wave = wsz * 2 + lsz + xsz + hssz + fsz + 1024;

  if (ws_size >= need_wave) {
    // -------- layer-wavefront path --------
    size_t off = 0;
    __hip_bfloat16* wih_b = (__hip_bfloat16*)(ws + off); off += wsz;
    __hip_bfloat16* whh_hi = (__hip_bfloat16*)(ws + off); off += wsz;
    __hip_bfloat16* whh_lo = (__hip_bfloat16*)(ws + off); off += lsz;
    __hip_bfloat16* xb = (__hip_bfloat16*)(ws + off); off += xsz;
    __hip_bfloat16* hseq = (__hip_bfloat16*)(ws + off); off += hssz;
    int* flags = (int*)(ws + off); off += fsz;

    {
      size_t n = (size_t)NL * N3H * NH;
      conv_w_kernel<<<dim3((n + 255) / 256), dim3(256), 0, stream>>>(
          w_ih, w_hh, wih_b, whh_hi, whh_lo);
    }
    {
      size_t n = (size_t)NT * NB * NH;
      conv_x_kernel<<<dim3((n + 255) / 256), dim3(256), 0, stream>>>(x, xb);
    }
    {
      size_t n = (size_t)NL * NB * NH;
      init_wave_kernel<<<dim3((n + 255) / 256), dim3(256), 0, stream>>>(
          h0, out, hseq, flags);
    }
    gru_wave_kernel<<<dim3(256), dim3(128), 0, stream>>>(
        whh_hi, whh_lo, wih_b, xb, b_ih, b_hh, hseq, out, flags);
    return;
  }

  // -------- fallback: previous verified chunked path --------
  size_t off = 0;
  const size_t ssz = (size_t)NT * NB * NH * 2;
  __hip_bfloat16* wih_b = (__hip_bfloat16*)(ws + off); off += wsz;
  __hip_bfloat16* whh_hi = (__hip_bfloat16*)(ws + off); off += wsz;
  __hip_bfloat16* whh_lo = (__hip_bfloat16*)(ws + off); off += lsz;
  __hip_bfloat16* seqA = (__hip_bfloat16*)(ws + off); off += ssz;
  __hip_bfloat16* seqB = (__hip_bfloat16*)(ws + off); off += ssz;
  __hip_bfloat16* hbuf = (__hip_bfloat16*)(ws + off); off += (size_t)2 * NB * NH * 2;
  int* flags = (int*)(ws + off); off += (size_t)4 * 64 * FSTRIDE * 4;
  off = (off + 255) & ~(size_t)255;
  float* gi_buf = (float*)(ws + off);

  long long avail = (long long)ws_size - (long long)off;
  int TC = 256;
  while (TC > 2 && (long long)TC * NB * N3H * 4 > avail) TC >>= 1;

  {
    size_t n = (size_t)NL * N3H * NH;
    conv_w_kernel<<<dim3((n + 255) / 256), dim3(256), 0, stream>>>(
        w_ih, w_hh, wih_b, whh_hi, whh_lo);
  }
  {
    size_t n = (size_t)NT * NB * NH;
    conv_x_kernel<<<dim3((n + 255) / 256), dim3(256), 0, stream>>>(x, seqA);
  }
  {
    size_t n = (size_t)NL * NB * NH;
    init_out_kernel<<<dim3((n + 255) / 256), dim3(256), 0, stream>>>(h0, out, flags);
  }

  const size_t bh = (size_t)NB * NH;
  const int nchunks = NT / TC;
  for (int l = 0; l < NL; ++l) {
    init_hbf_kernel<<<dim3((bh + 255) / 256), dim3(256), 0, stream>>>(
        h0 + (size_t)l * bh, hbuf);
    const __hip_bfloat16* cur = (l & 1) ? seqB : seqA;
    __hip_bfloat16* nxt = (l == NL - 1) ? (__hip_bfloat16*)nullptr
                                        : ((l & 1) ? seqA : seqB);
    const __hip_bfloat16* wih_l = wih_b + (size_t)l * N3H * NH;
    const __hip_bfloat16* whha_l = whh_hi + (size_t)l * N3H * NH;
    const __hip_bfloat16* whhb_l = whh_lo + (size_t)l * NH * NH;
    const float* bih_l = b_ih + (size_t)l * N3H;
    const float* bhh_l = b_hh + (size_t)l * N3H;
    float* hfp_l = out + (size_t)l * bh;
    for (int c = 0; c < nchunks; ++c) {
      const __hip_bfloat16* Ac = cur + (size_t)c * TC * bh;
      gemm_gi_kernel<<<dim3(TC * NB / 128, N3H / 128), dim3(256), 0, stream>>>(
          Ac, wih_l, bih_l, gi_buf);
      __hip_bfloat16* so = nxt ? nxt + (size_t)c * TC * bh : (__hip_bfloat16*)nullptr;
      gru_persist_kernel<<<dim3(256), dim3(64), 0, stream>>>(
          whha_l, whhb_l, gi_buf, bhh_l, hbuf, so, hfp_l, flags,
          l * NT + c * TC, TC);
    }
  }
}

// Round 3
// 13111.288 us; speedup vs baseline: 2.0904x; 1.1777x over previous
//
#include <hip/hip_runtime.h>
#include <hip/hip_bf16.h>

#define NL 4
#define NB 64
#define NT 512
#define NH 1024
#define N3H 3072
#define BH 65536            // NB*NH
#define HS_SLOTS 513        // h0 + 512 steps
#define FSTRIDE 4           // ints per flag slot (16 B padding)

typedef __attribute__((ext_vector_type(8))) short short8;
typedef __attribute__((ext_vector_type(4))) float floatx4;

__device__ __forceinline__ short8 ld8(const __hip_bfloat16* p) {
  return *(const short8*)p;
}

// ---------------- prep kernels (shared) ----------------

// w_ih -> bf16 ; w_hh -> bf16 hi (all rows) + bf16 lo (n-gate rows only)
__global__ void conv_w_kernel(const float* __restrict__ w_ih,
                              const float* __restrict__ w_hh,
                              __hip_bfloat16* __restrict__ wih_b,
                              __hip_bfloat16* __restrict__ whh_hi,
                              __hip_bfloat16* __restrict__ whh_lo_n) {
  size_t i = (size_t)blockIdx.x * 256 + threadIdx.x;
  if (i >= (size_t)NL * N3H * NH) return;
  wih_b[i] = __float2bfloat16(w_ih[i]);
  float v = w_hh[i];
  __hip_bfloat16 hi = __float2bfloat16(v);
  whh_hi[i] = hi;
  size_t l = i / ((size_t)N3H * NH);
  size_t rem = i - l * ((size_t)N3H * NH);
  size_t row = rem / NH;
  if (row >= (size_t)2 * NH) {
    size_t k = rem - row * NH;
    whh_lo_n[(l * NH + (row - 2 * NH)) * NH + k] =
        __float2bfloat16(v - __bfloat162float(hi));
  }
}

__global__ void conv_x_kernel(const float* __restrict__ x,
                              __hip_bfloat16* __restrict__ xb) {
  size_t i = (size_t)blockIdx.x * 256 + threadIdx.x;
  if (i >= (size_t)NT * NB * NH) return;
  xb[i] = __float2bfloat16(x[i]);
}

// ---------------- wavefront-path init ----------------
__global__ void init_wave_kernel(const float* __restrict__ h0,
                                 float* __restrict__ out,
                                 __hip_bfloat16* __restrict__ hseq,
                                 int* __restrict__ flags) {
  size_t i = (size_t)blockIdx.x * 256 + threadIdx.x;
  if (i < (size_t)5 * 64 * FSTRIDE)
    flags[i] = (i < (size_t)4 * 64 * FSTRIDE) ? 0 : 0x3fffffff;
  if (i >= (size_t)NL * NB * NH) return;
  out[i] = h0[i];
  size_t l = i >> 16;          // / BH
  size_t j = i & (BH - 1);
  hseq[l * (size_t)HS_SLOTS * BH + j] = __float2bfloat16(h0[i]);
}

// ---------------- layer-wavefront persistent kernel ----------------
// Grid: 256 blocks x 256 threads (4 waves). Block (l,g) owns u-cols
// [g*16,g*16+16) of layer l; wave wv owns batch rows [wv*16, wv*16+16).
// LDS (128 KB dynamic) holds ALL whh operand streams: n-gate hi+lo, r, z.
// Only vr/vz/vn (96 KB/block) stream from cache: 32 blocks/XCD x 96 KB
// = 3 MB < 4 MB L2 -> weight stream stays L2-warm (round-2's 23 MB/tick
// HBM thrash came from the 5 MB/XCD overflow with wr/wz in the stream).
__global__ __launch_bounds__(256, 1) void gru_wave_kernel(
    const __hip_bfloat16* __restrict__ whh_hi,  // [L][3072][1024]
    const __hip_bfloat16* __restrict__ whh_lo,  // [L][1024][1024] n-gate lo
    const __hip_bfloat16* __restrict__ wih,     // [L][3072][1024]
    const __hip_bfloat16* __restrict__ xb,      // [512][64][1024]
    const float* __restrict__ b_ih,             // [L][3072]
    const float* __restrict__ b_hh,             // [L][3072]
    __hip_bfloat16* hseq,                       // [L][513][64][1024]
    float* __restrict__ out,                    // [L][64][1024]
    int* flags) {                               // [5][64][FSTRIDE]
  extern __shared__ short lds[];  // [4][32 kc][64 lane][8 bf16] = 128 KB
  const int tid = threadIdx.x;
  const int wv = tid >> 6, lane = tid & 63;
  const int l = blockIdx.x >> 6, g = blockIdx.x & 63;
  const int l15 = lane & 15, quad = lane >> 4;
  const int u = g * 16 + l15;

  const size_t l3h = (size_t)l * N3H;

  // stage whh frags: wave0->n-hi, wave1->n-lo, wave2->r, wave3->z
  // (fragment order [kc][lane][8]: conflict-free ds_read_b128)
  {
    const __hip_bfloat16* src;
    if (wv == 0)      src = whh_hi + (l3h + 2 * NH + u) * NH + quad * 8;
    else if (wv == 1) src = whh_lo + (((size_t)l * NH) + u) * NH + quad * 8;
    else if (wv == 2) src = whh_hi + (l3h + u) * NH + quad * 8;
    else              src = whh_hi + (l3h + NH + u) * NH + quad * 8;
    short* dst = lds + wv * 16384 + lane * 8;
#pragma unroll 4
    for (int kc = 0; kc < 32; ++kc)
      *(short8*)(dst + kc * 512) = ld8(src + kc * 32);
  }
  __syncthreads();

  const __hip_bfloat16* vr = wih + (l3h + u) * NH + quad * 8;
  const __hip_bfloat16* vz = wih + (l3h + NH + u) * NH + quad * 8;
  const __hip_bfloat16* vn = wih + (l3h + 2 * NH + u) * NH + quad * 8;
  const float bir = b_ih[l3h + u], biz = b_ih[l3h + NH + u],
              bin = b_ih[l3h + 2 * NH + u];
  const float bhr = b_hh[l3h + u], bhz = b_hh[l3h + NH + u],
              bhn = b_hh[l3h + 2 * NH + u];

  __hip_bfloat16* hs_l = hseq + (size_t)l * HS_SLOTS * BH;
  const __hip_bfloat16* upbase =
      l ? hseq + (size_t)(l - 1) * HS_SLOTS * BH : xb;
  const int upoff = l ? 1 : 0;  // l>0 reads upstream slot t+1 (h_{l-1}(t))

  const int row0 = wv * 16 + quad * 4;                          // + r
  const size_t arow = (size_t)(wv * 16 + l15) * NH + quad * 8;  // A-frag base

  // fp32 master copy of this thread's 4 output elements
  float hreg[4];
#pragma unroll
  for (int r = 0; r < 4; ++r)
    hreg[r] = out[(size_t)l * BH + (size_t)(row0 + r) * NH + u];

  const int* fo = flags + (l * 64 + lane) * FSTRIDE;                  // own
  const int* fu = flags + ((l ? (l - 1) : 4) * 64 + lane) * FSTRIDE;  // upstream
  int* fmine = flags + (l * 64 + g) * FSTRIDE;

#pragma unroll 1
  for (int t = 0; t < NT; ++t) {
    // wait: own layer published h(t-1) (flag >= t), upstream published h_up(t)
    while (__hip_atomic_load(fo, __ATOMIC_RELAXED, __HIP_MEMORY_SCOPE_AGENT) < t)
      __builtin_amdgcn_s_sleep(1);
    while (__hip_atomic_load(fu, __ATOMIC_RELAXED, __HIP_MEMORY_SCOPE_AGENT) < t + 1)
      __builtin_amdgcn_s_sleep(1);
    // forbid hoisting any h load above the spins
    __builtin_amdgcn_sched_barrier(0);
    asm volatile("" ::: "memory");

    const __hip_bfloat16* ob = hs_l + (size_t)t * BH + arow;
    const __hip_bfloat16* ub = upbase + (size_t)(t + upoff) * BH + arow;

    floatx4 z4 = {0.f, 0.f, 0.f, 0.f};
    floatx4 ar = z4, az = z4, anh = z4, anl = z4, gr = z4, gz = z4, gn = z4;

#pragma unroll 4
    for (int kc = 0; kc < 32; ++kc) {
      short8 ho = ld8(ob + kc * 32);
      short8 hu = ld8(ub + kc * 32);
      short8 vrf = ld8(vr + kc * 32);
      short8 vzf = ld8(vz + kc * 32);
      short8 vnf = ld8(vn + kc * 32);
      short8 bnh = *(short8*)(lds + lane * 8 + kc * 512);
      short8 bnl = *(short8*)(lds + 16384 + lane * 8 + kc * 512);
      short8 brf = *(short8*)(lds + 32768 + lane * 8 + kc * 512);
      short8 bzf = *(short8*)(lds + 49152 + lane * 8 + kc * 512);
      ar = __builtin_amdgcn_mfma_f32_16x16x32_bf16(ho, brf, ar, 0, 0, 0);
      az = __builtin_amdgcn_mfma_f32_16x16x32_bf16(ho, bzf, az, 0, 0, 0);
      anh = __builtin_amdgcn_mfma_f32_16x16x32_bf16(ho, bnh, anh, 0, 0, 0);
      anl = __builtin_amdgcn_mfma_f32_16x16x32_bf16(ho, bnl, anl, 0, 0, 0);
      gr = __builtin_amdgcn_mfma_f32_16x16x32_bf16(hu, vrf, gr, 0, 0, 0);
      gz = __builtin_amdgcn_mfma_f32_16x16x32_bf16(hu, vzf, gz, 0, 0, 0);
      gn = __builtin_amdgcn_mfma_f32_16x16x32_bf16(hu, vnf, gn, 0, 0, 0);
    }

    __hip_bfloat16* hw = hs_l + (size_t)(t + 1) * BH;
#pragma unroll
    for (int r = 0; r < 4; ++r) {
      float ghr = ar[r] + bhr;
      float ghz = az[r] + bhz;
      float ghn = anh[r] + anl[r] + bhn;
      float gir = gr[r] + bir;
      float giz = gz[r] + biz;
      float gin = gn[r] + bin;
      float rr = 1.f / (1.f + __expf(-(gir + ghr)));
      float zz = 1.f / (1.f + __expf(-(giz + ghz)));
      float xt = gin + rr * ghn;
      xt = fminf(fmaxf(xt, -15.f), 15.f);
      float e2 = __expf(2.f * xt);
      float nn = (e2 - 1.f) / (e2 + 1.f);
      float hn = (1.f - zz) * nn + zz * hreg[r];
      hreg[r] = hn;
      __hip_bfloat16 hb16 = __float2bfloat16(hn);
      unsigned int v32 = (unsigned int)__builtin_bit_cast(unsigned short, hb16);
      // write-through to the LLC so vmcnt(0) is a full release
      asm volatile("global_store_short %0, %1, off sc0 sc1"
                   :: "v"(hw + (size_t)(row0 + r) * NH + u), "v"(v32)
                   : "memory");
    }
    asm volatile("s_waitcnt vmcnt(0)" ::: "memory");  // h visible at LLC
    __syncthreads();                                  // all 4 waves done
    if (tid == 0)
      __hip_atomic_store(fmine, t + 1, __ATOMIC_RELAXED, __HIP_MEMORY_SCOPE_AGENT);
  }

#pragma unroll
  for (int r = 0; r < 4; ++r)
    out[(size_t)l * BH + (size_t)(row0 + r) * NH + u] = hreg[r];
}

// ================= fallback path (previous verified kernel) =================

__global__ void init_out_kernel(const float* __restrict__ h0,
                                float* __restrict__ out,
                                int* __restrict__ flags) {
  size_t i = (size_t)blockIdx.x * 256 + threadIdx.x;
  if (i < (size_t)4 * 64 * FSTRIDE) flags[i] = 0;
  if (i >= (size_t)NL * NB * NH) return;
  out[i] = h0[i];
}

__global__ void init_hbf_kernel(const float* __restrict__ h0_layer,
                                __hip_bfloat16* __restrict__ hb) {
  size_t i = (size_t)blockIdx.x * 256 + threadIdx.x;
  if (i >= (size_t)NB * NH) return;
  hb[i] = __float2bfloat16(h0_layer[i]);
}

__global__ __launch_bounds__(256) void gemm_gi_kernel(
    const __hip_bfloat16* __restrict__ A,
    const __hip_bfloat16* __restrict__ Wb,
    const float* __restrict__ bih,
    float* __restrict__ C) {
  __shared__ short lA[128 * 32];
  __shared__ short lB[128 * 32];
  const int tid = threadIdx.x;
  const int wave = tid >> 6, lane = tid & 63;
  const int l15 = lane & 15, quad = lane >> 4;
  const int m0 = blockIdx.x * 128;
  const int n0 = blockIdx.y * 128;
  const int wm = (wave >> 1) * 64, wn = (wave & 1) * 64;

  const int r1 = tid >> 2, c1 = (tid & 3) * 8;
  const __hip_bfloat16* Arow0 = A + (size_t)(m0 + r1) * NH + c1;
  const __hip_bfloat16* Arow1 = A + (size_t)(m0 + r1 + 64) * NH + c1;
  const __hip_bfloat16* Brow0 = Wb + (size_t)(n0 + r1) * NH + c1;
  const __hip_bfloat16* Brow1 = Wb + (size_t)(n0 + r1 + 64) * NH + c1;

  floatx4 z4 = {0.f, 0.f, 0.f, 0.f};
  floatx4 acc[4][4];
#pragma unroll
  for (int mi = 0; mi < 4; ++mi)
#pragma unroll
    for (int ni = 0; ni < 4; ++ni) acc[mi][ni] = z4;

  for (int kt = 0; kt < 32; ++kt) {
    const int ko = kt * 32;
    short8 a0 = ld8(Arow0 + ko), a1 = ld8(Arow1 + ko);
    short8 b0 = ld8(Brow0 + ko), b1 = ld8(Brow1 + ko);
    __syncthreads();
    *(short8*)(lA + tid * 8) = a0;
    *(short8*)(lA + (tid + 256) * 8) = a1;
    *(short8*)(lB + tid * 8) = b0;
    *(short8*)(lB + (tid + 256) * 8) = b1;
    __syncthreads();
    short8 af[4], bf[4];
#pragma unroll
    for (int mi = 0; mi < 4; ++mi)
      af[mi] = *(short8*)(lA + (wm + mi * 16 + l15) * 32 + quad * 8);
#pragma unroll
    for (int ni = 0; ni < 4; ++ni)
      bf[ni] = *(short8*)(lB + (wn + ni * 16 + l15) * 32 + quad * 8);
#pragma unroll
    for (int mi = 0; mi < 4; ++mi)
#pragma unroll
      for (int ni = 0; ni < 4; ++ni)
        acc[mi][ni] =
            __builtin_amdgcn_mfma_f32_16x16x32_bf16(af[mi], bf[ni], acc[mi][ni], 0, 0, 0);
  }

  const int crow = m0 + wm + quad * 4;
#pragma unroll
  for (int ni = 0; ni < 4; ++ni) {
    const int col = n0 + wn + ni * 16 + l15;
    const float bias = bih[col];
#pragma unroll
    for (int mi = 0; mi < 4; ++mi)
#pragma unroll
      for (int r = 0; r < 4; ++r)
        C[(size_t)(crow + mi * 16 + r) * N3H + col] = acc[mi][ni][r] + bias;
  }
}

__global__ __launch_bounds__(64) void gru_persist_kernel(
    const __hip_bfloat16* __restrict__ whh_hi_l,
    const __hip_bfloat16* __restrict__ whh_lo_l,
    const float* __restrict__ gi_c,
    const float* __restrict__ bhh_l,
    __hip_bfloat16* hbuf,
    __hip_bfloat16* seq_out,
    float* hfp,
    int* flags,
    int s0, int nsteps) {
  const int lane = threadIdx.x;
  const int w = blockIdx.x >> 6;
  const int g = blockIdx.x & 63;
  const int l15 = lane & 15, quad = lane >> 4;
  const int u = g * 16 + l15;

  __shared__ short lds_s[32768];

  {
    const __hip_bfloat16* srch = whh_hi_l + ((size_t)(2 * NH) + u) * NH + quad * 8;
    const __hip_bfloat16* srcl = whh_lo_l + (size_t)u * NH + quad * 8;
    short* dst = lds_s + lane * 8;
#pragma unroll 4
    for (int kc = 0; kc < 32; ++kc) {
      *(short8*)(dst + kc * 512) = ld8(srch + kc * 32);
      *(short8*)(dst + 16384 + kc * 512) = ld8(srcl + kc * 32);
    }
  }
  __syncthreads();

  const int bb = w * 16 + quad * 4;
  float hreg[4];
#pragma unroll
  for (int r = 0; r < 4; ++r) hreg[r] = hfp[(size_t)(bb + r) * NH + u];

  const float bhr = bhh_l[u], bhz = bhh_l[NH + u], bhn = bhh_l[2 * NH + u];
  const __hip_bfloat16* wr = whh_hi_l + (size_t)u * NH + quad * 8;
  const __hip_bfloat16* wz = whh_hi_l + ((size_t)NH + u) * NH + quad * 8;

  int* myflag = flags + (w * 64 + lane) * FSTRIDE;
  int* outflag = flags + (w * 64 + g) * FSTRIDE;
  __hip_bfloat16* hb0 = hbuf;
  __hip_bfloat16* hb1 = hbuf + NB * NH;

  for (int s = s0; s < s0 + nsteps; ++s) {
    const int tc = s - s0;
    const float* gp = gi_c + ((size_t)tc * NB + bb) * N3H + u;
    float gi_r[4], gi_z[4], gi_n[4];
#pragma unroll
    for (int r = 0; r < 4; ++r) {
      gi_r[r] = gp[(size_t)r * N3H];
      gi_z[r] = gp[(size_t)r * N3H + NH];
      gi_n[r] = gp[(size_t)r * N3H + 2 * NH];
    }

    while (__hip_atomic_load(myflag, __ATOMIC_RELAXED, __HIP_MEMORY_SCOPE_AGENT) < s)
      __builtin_amdgcn_s_sleep(1);

    const __hip_bfloat16* hbase =
        ((s & 1) ? hb1 : hb0) + (size_t)(w * 16 + l15) * NH + quad * 8;
    short8 hf[32];
#pragma unroll
    for (int kc = 0; kc < 32; ++kc)
      asm volatile("global_load_dwordx4 %0, %1, off sc0 sc1"
                   : "=v"(hf[kc]) : "v"(hbase + kc * 32));
#pragma unroll
    for (int g8 = 0; g8 < 32; g8 += 8)
      asm volatile("s_waitcnt vmcnt(0)"
                   : "+v"(hf[g8]), "+v"(hf[g8 + 1]), "+v"(hf[g8 + 2]),
                     "+v"(hf[g8 + 3]), "+v"(hf[g8 + 4]), "+v"(hf[g8 + 5]),
                     "+v"(hf[g8 + 6]), "+v"(hf[g8 + 7])
                   :: "memory");

    floatx4 accr = {0.f, 0.f, 0.f, 0.f}, accz = accr, accnh = accr, accnl = accr;
#pragma unroll 8
    for (int kc = 0; kc < 32; ++kc) {
      short8 ah = hf[kc];
      short8 brf = ld8(wr + kc * 32);
      short8 bzf = ld8(wz + kc * 32);
      short8 bnh = *(short8*)(lds_s + lane * 8 + kc * 512);
      short8 bnl = *(short8*)(lds_s + 16384 + lane * 8 + kc * 512);
      accr = __builtin_amdgcn_mfma_f32_16x16x32_bf16(ah, brf, accr, 0, 0, 0);
      accz = __builtin_amdgcn_mfma_f32_16x16x32_bf16(ah, bzf, accz, 0, 0, 0);
      accnh = __builtin_amdgcn_mfma_f32_16x16x32_bf16(ah, bnh, accnh, 0, 0, 0);
      accnl = __builtin_amdgcn_mfma_f32_16x16x32_bf16(ah, bnl, accnl, 0, 0, 0);
    }

    __hip_bfloat16* hout = (s & 1) ? hb0 : hb1;
#pragma unroll
    for (int r = 0; r < 4; ++r) {
      float ghr = accr[r] + bhr;
      float ghz = accz[r] + bhz;
      float ghn = accnh[r] + accnl[r] + bhn;
      float rr = 1.f / (1.f + __expf(-(gi_r[r] + ghr)));
      float zz = 1.f / (1.f + __expf(-(gi_z[r] + ghz)));
      float xt = gi_n[r] + rr * ghn;
      xt = fminf(fmaxf(xt, -15.f), 15.f);
      float e2 = __expf(2.f * xt);
      float nn = (e2 - 1.f) / (e2 + 1.f);
      float hn = (1.f - zz) * nn + zz * hreg[r];
      hreg[r] = hn;
      __hip_bfloat16 hb16 = __float2bfloat16(hn);
      size_t idx = (size_t)(bb + r) * NH + u;
      unsigned int v32 = (unsigned int)__builtin_bit_cast(unsigned short, hb16);
      asm volatile("global_store_short %0, %1, off sc0 sc1"
                   :: "v"(hout + idx), "v"(v32) : "memory");
      if (seq_out) seq_out[(size_t)tc * (NB * NH) + idx] = hb16;
    }
    asm volatile("s_waitcnt vmcnt(0)" ::: "memory");
    if (lane == 0)
      __hip_atomic_store(outflag, s + 1, __ATOMIC_RELAXED, __HIP_MEMORY_SCOPE_AGENT);
  }

#pragma unroll
  for (int r = 0; r < 4; ++r) hfp[(size_t)(bb + r) * NH + u] = hreg[r];
}

// ---------------- launch ----------------
extern "C" void kernel_launch(void* const* d_in, const int* in_sizes, int n_in,
                              void* d_out, int out_size, void* d_ws, size_t ws_size,
                              hipStream_t stream) {
  const float* x = (const float*)d_in[0];
  const float* h0 = (const float*)d_in[1];
  const float* w_ih = (const float*)d_in[2];
  const float* w_hh = (const float*)d_in[3];
  const float* b_ih = (const float*)d_in[4];
  const float* b_hh = (const float*)d_in[5];
  float* out = (float*)d_out;
  (void)in_sizes; (void)n_in; (void)out_size;

  char* ws = (char*)d_ws;
  const size_t wsz = (size_t)NL * N3H * NH * 2;   // 25.2 MB
  const size_t lsz = (size_t)NL * NH * NH * 2;    // 8.4 MB
  const size_t xsz = (size_t)NT * NB * NH * 2;    // 67.1 MB
  const size_t hssz = (size_t)NL * HS_SLOTS * BH * 2;  // 269.0 MB
  const size_t fsz = (size_t)5 * 64 * FSTRIDE * 4;
  const size_t need_wave = wsz * 2 + lsz + xsz + hssz + fsz + 1024;

  if (ws_size >= need_wave) {
    // -------- layer-wavefront path --------
    size_t off = 0;
    __hip_bfloat16* wih_b = (__hip_bfloat16*)(ws + off); off += wsz;
    __hip_bfloat16* whh_hi = (__hip_bfloat16*)(ws + off); off += wsz;
    __hip_bfloat16* whh_lo = (__hip_bfloat16*)(ws + off); off += lsz;
    __hip_bfloat16* xb = (__hip_bfloat16*)(ws + off); off += xsz;
    __hip_bfloat16* hseq = (__hip_bfloat16*)(ws + off); off += hssz;
    int* flags = (int*)(ws + off); off += fsz;

    static bool attr_set = false;
    if (!attr_set) {
      (void)hipFuncSetAttribute((const void*)gru_wave_kernel,
                                hipFuncAttributeMaxDynamicSharedMemorySize,
                                131072);
      attr_set = true;
    }

    {
      size_t n = (size_t)NL * N3H * NH;
      conv_w_kernel<<<dim3((n + 255) / 256), dim3(256), 0, stream>>>(
          w_ih, w_hh, wih_b, whh_hi, whh_lo);
    }
    {
      size_t n = (size_t)NT * NB * NH;
      conv_x_kernel<<<dim3((n + 255) / 256), dim3(256), 0, stream>>>(x, xb);
    }
    {
      size_t n = (size_t)NL * NB * NH;
      init_wave_kernel<<<dim3((n + 255) / 256), dim3(256), 0, stream>>>(
          h0, out, hseq, flags);
    }
    gru_wave_kernel<<<dim3(256), dim3(256), 131072, stream>>>(
        whh_hi, whh_lo, wih_b, xb, b_ih, b_hh, hseq, out, flags);
    return;
  }

  // -------- fallback: previous verified chunked path --------
  size_t off = 0;
  const size_t ssz = (size_t)NT * NB * NH * 2;
  __hip_bfloat16* wih_b = (__hip_bfloat16*)(ws + off); off += wsz;
  __hip_bfloat16* whh_hi = (__hip_bfloat16*)(ws + off); off += wsz;
  __hip_bfloat16* whh_lo = (__hip_bfloat16*)(ws + off); off += lsz;
  __hip_bfloat16* seqA = (__hip_bfloat16*)(ws + off); off += ssz;
  __hip_bfloat16* seqB = (__hip_bfloat16*)(ws + off); off += ssz;
  __hip_bfloat16* hbuf = (__hip_bfloat16*)(ws + off); off += (size_t)2 * NB * NH * 2;
  int* flags = (int*)(ws + off); off += (size_t)4 * 64 * FSTRIDE * 4;
  off = (off + 255) & ~(size_t)255;
  float* gi_buf = (float*)(ws + off);

  long long avail = (long long)ws_size - (long long)off;
  int TC = 256;
  while (TC > 2 && (long long)TC * NB * N3H * 4 > avail) TC >>= 1;

  {
    size_t n = (size_t)NL * N3H * NH;
    conv_w_kernel<<<dim3((n + 255) / 256), dim3(256), 0, stream>>>(
        w_ih, w_hh, wih_b, whh_hi, whh_lo);
  }
  {
    size_t n = (size_t)NT * NB * NH;
    conv_x_kernel<<<dim3((n + 255) / 256), dim3(256), 0, stream>>>(x, seqA);
  }
  {
    size_t n = (size_t)NL * NB * NH;
    init_out_kernel<<<dim3((n + 255) / 256), dim3(256), 0, stream>>>(h0, out, flags);
  }

  const size_t bh = (size_t)NB * NH;
  const int nchunks = NT / TC;
  for (int l = 0; l < NL; ++l) {
    init_hbf_kernel<<<dim3((bh + 255) / 256), dim3(256), 0, stream>>>(
        h0 + (size_t)l * bh, hbuf);
    const __hip_bfloat16* cur = (l & 1) ? seqB : seqA;
    __hip_bfloat16* nxt = (l == NL - 1) ? (__hip_bfloat16*)nullptr
                                        : ((l & 1) ? seqA : seqB);
    const __hip_bfloat16* wih_l = wih_b + (size_t)l * N3H * NH;
    const __hip_bfloat16* whha_l = whh_hi + (size_t)l * N3H * NH;
    const __hip_bfloat16* whhb_l = whh_lo + (size_t)l * NH * NH;
    const float* bih_l = b_ih + (size_t)l * N3H;
    const float* bhh_l = b_hh + (size_t)l * N3H;
    float* hfp_l = out + (size_t)l * bh;
    for (int c = 0; c < nchunks; ++c) {
      const __hip_bfloat16* Ac = cur + (size_t)c * TC * bh;
      gemm_gi_kernel<<<dim3(TC * NB / 128, N3H / 128), dim3(256), 0, stream>>>(
          Ac, wih_l, bih_l, gi_buf);
      __hip_bfloat16* so = nxt ? nxt + (size_t)c * TC * bh : (__hip_bfloat16*)nullptr;
      gru_persist_kernel<<<dim3(256), dim3(64), 0, stream>>>(
          whha_l, whhb_l, gi_buf, bhh_l, hbuf, so, hfp_l, flags,
          l * NT + c * TC, TC);
    }
  }
}

// Round 4
// 10555.596 us; speedup vs baseline: 2.5966x; 1.2421x over previous
//
#include <hip/hip_runtime.h>
#include <hip/hip_bf16.h>

#define NL 4
#define NB 64
#define NT 512
#define NH 1024
#define N3H 3072
#define BH 65536            // NB*NH
#define HS_SLOTS 513        // h0 + 512 steps
#define FSTRIDE 4           // ints per flag slot (16 B padding)

typedef __attribute__((ext_vector_type(8))) short short8;
typedef __attribute__((ext_vector_type(4))) float floatx4;

__device__ __forceinline__ short8 ld8(const __hip_bfloat16* p) {
  return *(const short8*)p;
}

// ---------------- prep kernels (shared) ----------------

// w_ih -> bf16 ; w_hh -> bf16 hi (all rows) + bf16 lo (n-gate rows only)
__global__ void conv_w_kernel(const float* __restrict__ w_ih,
                              const float* __restrict__ w_hh,
                              __hip_bfloat16* __restrict__ wih_b,
                              __hip_bfloat16* __restrict__ whh_hi,
                              __hip_bfloat16* __restrict__ whh_lo_n) {
  size_t i = (size_t)blockIdx.x * 256 + threadIdx.x;
  if (i >= (size_t)NL * N3H * NH) return;
  wih_b[i] = __float2bfloat16(w_ih[i]);
  float v = w_hh[i];
  __hip_bfloat16 hi = __float2bfloat16(v);
  whh_hi[i] = hi;
  size_t l = i / ((size_t)N3H * NH);
  size_t rem = i - l * ((size_t)N3H * NH);
  size_t row = rem / NH;
  if (row >= (size_t)2 * NH) {
    size_t k = rem - row * NH;
    whh_lo_n[(l * NH + (row - 2 * NH)) * NH + k] =
        __float2bfloat16(v - __bfloat162float(hi));
  }
}

__global__ void conv_x_kernel(const float* __restrict__ x,
                              __hip_bfloat16* __restrict__ xb) {
  size_t i = (size_t)blockIdx.x * 256 + threadIdx.x;
  if (i >= (size_t)NT * NB * NH) return;
  xb[i] = __float2bfloat16(x[i]);
}

// ---------------- wavefront-path init ----------------
__global__ void init_wave_kernel(const float* __restrict__ h0,
                                 float* __restrict__ out,
                                 __hip_bfloat16* __restrict__ hseq,
                                 int* __restrict__ flags) {
  size_t i = (size_t)blockIdx.x * 256 + threadIdx.x;
  if (i < (size_t)5 * 64 * FSTRIDE)
    flags[i] = (i < (size_t)4 * 64 * FSTRIDE) ? 0 : 0x3fffffff;
  if (i >= (size_t)NL * NB * NH) return;
  out[i] = h0[i];
  size_t l = i >> 16;          // / BH
  size_t j = i & (BH - 1);
  hseq[l * (size_t)HS_SLOTS * BH + j] = __float2bfloat16(h0[i]);
}

// ---------------- layer-wavefront persistent kernel ----------------
// Grid: 256 blocks x 256 threads (4 waves). Block (l,g) owns u-cols
// [g*16,g*16+16) of layer l; wave wv owns batch rows [wv*16, wv*16+16).
// LDS (160 KB dynamic) holds 5 whh/wih operand streams: n-hi, n-lo, r, z, vn.
// Only vr/vz (64 KB) stream from L1/L2 per tick.
// Latency regime: 1 wave/SIMD + DVFS-downclocked chip -> every s_waitcnt is a
// dead SIMD. Fix: bulk-issue ALL ho/hu loads (ho[32], hu[32] register arrays)
// right after the spin -> ONE MALL-latency exposure per tick instead of 8
// (r1's proven hf[32] pattern), then a fully-unrolled MFMA loop on registers.
__global__ __launch_bounds__(256, 1) void gru_wave_kernel(
    const __hip_bfloat16* __restrict__ whh_hi,  // [L][3072][1024]
    const __hip_bfloat16* __restrict__ whh_lo,  // [L][1024][1024] n-gate lo
    const __hip_bfloat16* __restrict__ wih,     // [L][3072][1024]
    const __hip_bfloat16* __restrict__ xb,      // [512][64][1024]
    const float* __restrict__ b_ih,             // [L][3072]
    const float* __restrict__ b_hh,             // [L][3072]
    __hip_bfloat16* hseq,                       // [L][513][64][1024]
    float* __restrict__ out,                    // [L][64][1024]
    int* flags) {                               // [5][64][FSTRIDE]
  extern __shared__ short lds[];  // [5][32 kc][64 lane][8 bf16] = 160 KB
  const int tid = threadIdx.x;
  const int wv = tid >> 6, lane = tid & 63;
  const int l = blockIdx.x >> 6, g = blockIdx.x & 63;
  const int l15 = lane & 15, quad = lane >> 4;
  const int u = g * 16 + l15;

  const size_t l3h = (size_t)l * N3H;

  // stage streams: wave0->n-hi, wave1->n-lo, wave2->r, wave3->z (32 kc each)
  // + all 4 waves cooperatively stage vn (8 kc each). Fragment order
  // [kc][lane][8]: conflict-free ds_read_b128 (bank-conflict=0 measured).
  {
    const __hip_bfloat16* src;
    if (wv == 0)      src = whh_hi + (l3h + 2 * NH + u) * NH + quad * 8;
    else if (wv == 1) src = whh_lo + (((size_t)l * NH) + u) * NH + quad * 8;
    else if (wv == 2) src = whh_hi + (l3h + u) * NH + quad * 8;
    else              src = whh_hi + (l3h + NH + u) * NH + quad * 8;
    short* dst = lds + wv * 16384 + lane * 8;
#pragma unroll 4
    for (int kc = 0; kc < 32; ++kc)
      *(short8*)(dst + kc * 512) = ld8(src + kc * 32);
    // vn stream (stream 4): wave wv stages kc [8wv, 8wv+8)
    const __hip_bfloat16* srcn = wih + (l3h + 2 * NH + u) * NH + quad * 8;
    short* dstn = lds + 4 * 16384 + lane * 8;
#pragma unroll
    for (int kk = 0; kk < 8; ++kk) {
      int kc = wv * 8 + kk;
      *(short8*)(dstn + kc * 512) = ld8(srcn + kc * 32);
    }
  }
  __syncthreads();

  const __hip_bfloat16* vr = wih + (l3h + u) * NH + quad * 8;
  const __hip_bfloat16* vz = wih + (l3h + NH + u) * NH + quad * 8;
  const float bir = b_ih[l3h + u], biz = b_ih[l3h + NH + u],
              bin = b_ih[l3h + 2 * NH + u];
  const float bhr = b_hh[l3h + u], bhz = b_hh[l3h + NH + u],
              bhn = b_hh[l3h + 2 * NH + u];

  __hip_bfloat16* hs_l = hseq + (size_t)l * HS_SLOTS * BH;
  const __hip_bfloat16* upbase =
      l ? hseq + (size_t)(l - 1) * HS_SLOTS * BH : xb;
  const int upoff = l ? 1 : 0;  // l>0 reads upstream slot t+1 (h_{l-1}(t))

  const int row0 = wv * 16 + quad * 4;                          // + r
  const size_t arow = (size_t)(wv * 16 + l15) * NH + quad * 8;  // A-frag base

  // fp32 master copy of this thread's 4 output elements
  float hreg[4];
#pragma unroll
  for (int r = 0; r < 4; ++r)
    hreg[r] = out[(size_t)l * BH + (size_t)(row0 + r) * NH + u];

  const int* fo = flags + (l * 64 + lane) * FSTRIDE;                  // own
  const int* fu = flags + ((l ? (l - 1) : 4) * 64 + lane) * FSTRIDE;  // upstream
  int* fmine = flags + (l * 64 + g) * FSTRIDE;

#pragma unroll 1
  for (int t = 0; t < NT; ++t) {
    // combined wait: own layer published h(t-1) AND upstream published h_up(t)
    while (__hip_atomic_load(fo, __ATOMIC_RELAXED, __HIP_MEMORY_SCOPE_AGENT) < t ||
           __hip_atomic_load(fu, __ATOMIC_RELAXED, __HIP_MEMORY_SCOPE_AGENT) < t + 1)
      __builtin_amdgcn_s_sleep(1);
    // forbid hoisting any h load above the spins
    __builtin_amdgcn_sched_barrier(0);
    asm volatile("" ::: "memory");

    const __hip_bfloat16* ob = hs_l + (size_t)t * BH + arow;
    const __hip_bfloat16* ub = upbase + (size_t)(t + upoff) * BH + arow;

    // bulk-issue ALL h loads: one latency exposure for the whole tick
    short8 ho[32], hu[32];
#pragma unroll
    for (int kc = 0; kc < 32; ++kc) ho[kc] = ld8(ob + kc * 32);
#pragma unroll
    for (int kc = 0; kc < 32; ++kc) hu[kc] = ld8(ub + kc * 32);

    floatx4 z4 = {0.f, 0.f, 0.f, 0.f};
    floatx4 ar = z4, az = z4, anh = z4, anl = z4, gr = z4, gz = z4, gn = z4;

#pragma unroll
    for (int kc = 0; kc < 32; ++kc) {
      short8 vrf = ld8(vr + kc * 32);
      short8 vzf = ld8(vz + kc * 32);
      short8 bnh = *(short8*)(lds + lane * 8 + kc * 512);
      short8 bnl = *(short8*)(lds + 16384 + lane * 8 + kc * 512);
      short8 brf = *(short8*)(lds + 32768 + lane * 8 + kc * 512);
      short8 bzf = *(short8*)(lds + 49152 + lane * 8 + kc * 512);
      short8 vnf = *(short8*)(lds + 65536 + lane * 8 + kc * 512);
      ar = __builtin_amdgcn_mfma_f32_16x16x32_bf16(ho[kc], brf, ar, 0, 0, 0);
      az = __builtin_amdgcn_mfma_f32_16x16x32_bf16(ho[kc], bzf, az, 0, 0, 0);
      anh = __builtin_amdgcn_mfma_f32_16x16x32_bf16(ho[kc], bnh, anh, 0, 0, 0);
      anl = __builtin_amdgcn_mfma_f32_16x16x32_bf16(ho[kc], bnl, anl, 0, 0, 0);
      gr = __builtin_amdgcn_mfma_f32_16x16x32_bf16(hu[kc], vrf, gr, 0, 0, 0);
      gz = __builtin_amdgcn_mfma_f32_16x16x32_bf16(hu[kc], vzf, gz, 0, 0, 0);
      gn = __builtin_amdgcn_mfma_f32_16x16x32_bf16(hu[kc], vnf, gn, 0, 0, 0);
    }

    __hip_bfloat16* hw = hs_l + (size_t)(t + 1) * BH;
#pragma unroll
    for (int r = 0; r < 4; ++r) {
      float ghr = ar[r] + bhr;
      float ghz = az[r] + bhz;
      float ghn = anh[r] + anl[r] + bhn;
      float gir = gr[r] + bir;
      float giz = gz[r] + biz;
      float gin = gn[r] + bin;
      float rr = 1.f / (1.f + __expf(-(gir + ghr)));
      float zz = 1.f / (1.f + __expf(-(giz + ghz)));
      float xt = gin + rr * ghn;
      xt = fminf(fmaxf(xt, -15.f), 15.f);
      float e2 = __expf(2.f * xt);
      float nn = (e2 - 1.f) / (e2 + 1.f);
      float hn = (1.f - zz) * nn + zz * hreg[r];
      hreg[r] = hn;
      __hip_bfloat16 hb16 = __float2bfloat16(hn);
      unsigned int v32 = (unsigned int)__builtin_bit_cast(unsigned short, hb16);
      // write-through to the LLC so vmcnt(0) is a full release
      asm volatile("global_store_short %0, %1, off sc0 sc1"
                   :: "v"(hw + (size_t)(row0 + r) * NH + u), "v"(v32)
                   : "memory");
    }
    asm volatile("s_waitcnt vmcnt(0)" ::: "memory");  // h visible at LLC
    __syncthreads();                                  // all 4 waves done
    if (tid == 0)
      __hip_atomic_store(fmine, t + 1, __ATOMIC_RELAXED, __HIP_MEMORY_SCOPE_AGENT);
  }

#pragma unroll
  for (int r = 0; r < 4; ++r)
    out[(size_t)l * BH + (size_t)(row0 + r) * NH + u] = hreg[r];
}

// ================= fallback path (previous verified kernel) =================

__global__ void init_out_kernel(const float* __restrict__ h0,
                                float* __restrict__ out,
                                int* __restrict__ flags) {
  size_t i = (size_t)blockIdx.x * 256 + threadIdx.x;
  if (i < (size_t)4 * 64 * FSTRIDE) flags[i] = 0;
  if (i >= (size_t)NL * NB * NH) return;
  out[i] = h0[i];
}

__global__ void init_hbf_kernel(const float* __restrict__ h0_layer,
                                __hip_bfloat16* __restrict__ hb) {
  size_t i = (size_t)blockIdx.x * 256 + threadIdx.x;
  if (i >= (size_t)NB * NH) return;
  hb[i] = __float2bfloat16(h0_layer[i]);
}

__global__ __launch_bounds__(256) void gemm_gi_kernel(
    const __hip_bfloat16* __restrict__ A,
    const __hip_bfloat16* __restrict__ Wb,
    const float* __restrict__ bih,
    float* __restrict__ C) {
  __shared__ short lA[128 * 32];
  __shared__ short lB[128 * 32];
  const int tid = threadIdx.x;
  const int wave = tid >> 6, lane = tid & 63;
  const int l15 = lane & 15, quad = lane >> 4;
  const int m0 = blockIdx.x * 128;
  const int n0 = blockIdx.y * 128;
  const int wm = (wave >> 1) * 64, wn = (wave & 1) * 64;

  const int r1 = tid >> 2, c1 = (tid & 3) * 8;
  const __hip_bfloat16* Arow0 = A + (size_t)(m0 + r1) * NH + c1;
  const __hip_bfloat16* Arow1 = A + (size_t)(m0 + r1 + 64) * NH + c1;
  const __hip_bfloat16* Brow0 = Wb + (size_t)(n0 + r1) * NH + c1;
  const __hip_bfloat16* Brow1 = Wb + (size_t)(n0 + r1 + 64) * NH + c1;

  floatx4 z4 = {0.f, 0.f, 0.f, 0.f};
  floatx4 acc[4][4];
#pragma unroll
  for (int mi = 0; mi < 4; ++mi)
#pragma unroll
    for (int ni = 0; ni < 4; ++ni) acc[mi][ni] = z4;

  for (int kt = 0; kt < 32; ++kt) {
    const int ko = kt * 32;
    short8 a0 = ld8(Arow0 + ko), a1 = ld8(Arow1 + ko);
    short8 b0 = ld8(Brow0 + ko), b1 = ld8(Brow1 + ko);
    __syncthreads();
    *(short8*)(lA + tid * 8) = a0;
    *(short8*)(lA + (tid + 256) * 8) = a1;
    *(short8*)(lB + tid * 8) = b0;
    *(short8*)(lB + (tid + 256) * 8) = b1;
    __syncthreads();
    short8 af[4], bf[4];
#pragma unroll
    for (int mi = 0; mi < 4; ++mi)
      af[mi] = *(short8*)(lA + (wm + mi * 16 + l15) * 32 + quad * 8);
#pragma unroll
    for (int ni = 0; ni < 4; ++ni)
      bf[ni] = *(short8*)(lB + (wn + ni * 16 + l15) * 32 + quad * 8);
#pragma unroll
    for (int mi = 0; mi < 4; ++mi)
#pragma unroll
      for (int ni = 0; ni < 4; ++ni)
        acc[mi][ni] =
            __builtin_amdgcn_mfma_f32_16x16x32_bf16(af[mi], bf[ni], acc[mi][ni], 0, 0, 0);
  }

  const int crow = m0 + wm + quad * 4;
#pragma unroll
  for (int ni = 0; ni < 4; ++ni) {
    const int col = n0 + wn + ni * 16 + l15;
    const float bias = bih[col];
#pragma unroll
    for (int mi = 0; mi < 4; ++mi)
#pragma unroll
      for (int r = 0; r < 4; ++r)
        C[(size_t)(crow + mi * 16 + r) * N3H + col] = acc[mi][ni][r] + bias;
  }
}

__global__ __launch_bounds__(64) void gru_persist_kernel(
    const __hip_bfloat16* __restrict__ whh_hi_l,
    const __hip_bfloat16* __restrict__ whh_lo_l,
    const float* __restrict__ gi_c,
    const float* __restrict__ bhh_l,
    __hip_bfloat16* hbuf,
    __hip_bfloat16* seq_out,
    float* hfp,
    int* flags,
    int s0, int nsteps) {
  const int lane = threadIdx.x;
  const int w = blockIdx.x >> 6;
  const int g = blockIdx.x & 63;
  const int l15 = lane & 15, quad = lane >> 4;
  const int u = g * 16 + l15;

  __shared__ short lds_s[32768];

  {
    const __hip_bfloat16* srch = whh_hi_l + ((size_t)(2 * NH) + u) * NH + quad * 8;
    const __hip_bfloat16* srcl = whh_lo_l + (size_t)u * NH + quad * 8;
    short* dst = lds_s + lane * 8;
#pragma unroll 4
    for (int kc = 0; kc < 32; ++kc) {
      *(short8*)(dst + kc * 512) = ld8(srch + kc * 32);
      *(short8*)(dst + 16384 + kc * 512) = ld8(srcl + kc * 32);
    }
  }
  __syncthreads();

  const int bb = w * 16 + quad * 4;
  float hreg[4];
#pragma unroll
  for (int r = 0; r < 4; ++r) hreg[r] = hfp[(size_t)(bb + r) * NH + u];

  const float bhr = bhh_l[u], bhz = bhh_l[NH + u], bhn = bhh_l[2 * NH + u];
  const __hip_bfloat16* wr = whh_hi_l + (size_t)u * NH + quad * 8;
  const __hip_bfloat16* wz = whh_hi_l + ((size_t)NH + u) * NH + quad * 8;

  int* myflag = flags + (w * 64 + lane) * FSTRIDE;
  int* outflag = flags + (w * 64 + g) * FSTRIDE;
  __hip_bfloat16* hb0 = hbuf;
  __hip_bfloat16* hb1 = hbuf + NB * NH;

  for (int s = s0; s < s0 + nsteps; ++s) {
    const int tc = s - s0;
    const float* gp = gi_c + ((size_t)tc * NB + bb) * N3H + u;
    float gi_r[4], gi_z[4], gi_n[4];
#pragma unroll
    for (int r = 0; r < 4; ++r) {
      gi_r[r] = gp[(size_t)r * N3H];
      gi_z[r] = gp[(size_t)r * N3H + NH];
      gi_n[r] = gp[(size_t)r * N3H + 2 * NH];
    }

    while (__hip_atomic_load(myflag, __ATOMIC_RELAXED, __HIP_MEMORY_SCOPE_AGENT) < s)
      __builtin_amdgcn_s_sleep(1);

    const __hip_bfloat16* hbase =
        ((s & 1) ? hb1 : hb0) + (size_t)(w * 16 + l15) * NH + quad * 8;
    short8 hf[32];
#pragma unroll
    for (int kc = 0; kc < 32; ++kc)
      asm volatile("global_load_dwordx4 %0, %1, off sc0 sc1"
                   : "=v"(hf[kc]) : "v"(hbase + kc * 32));
#pragma unroll
    for (int g8 = 0; g8 < 32; g8 += 8)
      asm volatile("s_waitcnt vmcnt(0)"
                   : "+v"(hf[g8]), "+v"(hf[g8 + 1]), "+v"(hf[g8 + 2]),
                     "+v"(hf[g8 + 3]), "+v"(hf[g8 + 4]), "+v"(hf[g8 + 5]),
                     "+v"(hf[g8 + 6]), "+v"(hf[g8 + 7])
                   :: "memory");

    floatx4 accr = {0.f, 0.f, 0.f, 0.f}, accz = accr, accnh = accr, accnl = accr;
#pragma unroll 8
    for (int kc = 0; kc < 32; ++kc) {
      short8 ah = hf[kc];
      short8 brf = ld8(wr + kc * 32);
      short8 bzf = ld8(wz + kc * 32);
      short8 bnh = *(short8*)(lds_s + lane * 8 + kc * 512);
      short8 bnl = *(short8*)(lds_s + 16384 + lane * 8 + kc * 512);
      accr = __builtin_amdgcn_mfma_f32_16x16x32_bf16(ah, brf, accr, 0, 0, 0);
      accz = __builtin_amdgcn_mfma_f32_16x16x32_bf16(ah, bzf, accz, 0, 0, 0);
      accnh = __builtin_amdgcn_mfma_f32_16x16x32_bf16(ah, bnh, accnh, 0, 0, 0);
      accnl = __builtin_amdgcn_mfma_f32_16x16x32_bf16(ah, bnl, accnl, 0, 0, 0);
    }

    __hip_bfloat16* hout = (s & 1) ? hb0 : hb1;
#pragma unroll
    for (int r = 0; r < 4; ++r) {
      float ghr = accr[r] + bhr;
      float ghz = accz[r] + bhz;
      float ghn = accnh[r] + accnl[r] + bhn;
      float rr = 1.f / (1.f + __expf(-(gi_r[r] + ghr)));
      float zz = 1.f / (1.f + __expf(-(gi_z[r] + ghz)));
      float xt = gi_n[r] + rr * ghn;
      xt = fminf(fmaxf(xt, -15.f), 15.f);
      float e2 = __expf(2.f * xt);
      float nn = (e2 - 1.f) / (e2 + 1.f);
      float hn = (1.f - zz) * nn + zz * hreg[r];
      hreg[r] = hn;
      __hip_bfloat16 hb16 = __float2bfloat16(hn);
      size_t idx = (size_t)(bb + r) * NH + u;
      unsigned int v32 = (unsigned int)__builtin_bit_cast(unsigned short, hb16);
      asm volatile("global_store_short %0, %1, off sc0 sc1"
                   :: "v"(hout + idx), "v"(v32) : "memory");
      if (seq_out) seq_out[(size_t)tc * (NB * NH) + idx] = hb16;
    }
    asm volatile("s_waitcnt vmcnt(0)" ::: "memory");
    if (lane == 0)
      __hip_atomic_store(outflag, s + 1, __ATOMIC_RELAXED, __HIP_MEMORY_SCOPE_AGENT);
  }

#pragma unroll
  for (int r = 0; r < 4; ++r) hfp[(size_t)(bb + r) * NH + u] = hreg[r];
}

// ---------------- launch ----------------
extern "C" void kernel_launch(void* const* d_in, const int* in_sizes, int n_in,
                              void* d_out, int out_size, void* d_ws, size_t ws_size,
                              hipStream_t stream) {
  const float* x = (const float*)d_in[0];
  const float* h0 = (const float*)d_in[1];
  const float* w_ih = (const float*)d_in[2];
  const float* w_hh = (const float*)d_in[3];
  const float* b_ih = (const float*)d_in[4];
  const float* b_hh = (const float*)d_in[5];
  float* out = (float*)d_out;
  (void)in_sizes; (void)n_in; (void)out_size;

  char* ws = (char*)d_ws;
  const size_t wsz = (size_t)NL * N3H * NH * 2;   // 25.2 MB
  const size_t lsz = (size_t)NL * NH * NH * 2;    // 8.4 MB
  const size_t xsz = (size_t)NT * NB * NH * 2;    // 67.1 MB
  const size_t hssz = (size_t)NL * HS_SLOTS * BH * 2;  // 269.0 MB
  const size_t fsz = (size_t)5 * 64 * FSTRIDE * 4;
  const size_t need_wave = wsz * 2 + lsz + xsz + hssz + fsz + 1024;

  if (ws_size >= need_wave) {
    // -------- layer-wavefront path --------
    size_t off = 0;
    __hip_bfloat16* wih_b = (__hip_bfloat16*)(ws + off); off += wsz;
    __hip_bfloat16* whh_hi = (__hip_bfloat16*)(ws + off); off += wsz;
    __hip_bfloat16* whh_lo = (__hip_bfloat16*)(ws + off); off += lsz;
    __hip_bfloat16* xb = (__hip_bfloat16*)(ws + off); off += xsz;
    __hip_bfloat16* hseq = (__hip_bfloat16*)(ws + off); off += hssz;
    int* flags = (int*)(ws + off); off += fsz;

    static bool attr_set = false;
    if (!attr_set) {
      (void)hipFuncSetAttribute((const void*)gru_wave_kernel,
                                hipFuncAttributeMaxDynamicSharedMemorySize,
                                163840);
      attr_set = true;
    }

    {
      size_t n = (size_t)NL * N3H * NH;
      conv_w_kernel<<<dim3((n + 255) / 256), dim3(256), 0, stream>>>(
          w_ih, w_hh, wih_b, whh_hi, whh_lo);
    }
    {
      size_t n = (size_t)NT * NB * NH;
      conv_x_kernel<<<dim3((n + 255) / 256), dim3(256), 0, stream>>>(x, xb);
    }
    {
      size_t n = (size_t)NL * NB * NH;
      init_wave_kernel<<<dim3((n + 255) / 256), dim3(256), 0, stream>>>(
          h0, out, hseq, flags);
    }
    gru_wave_kernel<<<dim3(256), dim3(256), 163840, stream>>>(
        whh_hi, whh_lo, wih_b, xb, b_ih, b_hh, hseq, out, flags);
    return;
  }

  // -------- fallback: previous verified chunked path --------
  size_t off = 0;
  const size_t ssz = (size_t)NT * NB * NH * 2;
  __hip_bfloat16* wih_b = (__hip_bfloat16*)(ws + off); off += wsz;
  __hip_bfloat16* whh_hi = (__hip_bfloat16*)(ws + off); off += wsz;
  __hip_bfloat16* whh_lo = (__hip_bfloat16*)(ws + off); off += lsz;
  __hip_bfloat16* seqA = (__hip_bfloat16*)(ws + off); off += ssz;
  __hip_bfloat16* seqB = (__hip_bfloat16*)(ws + off); off += ssz;
  __hip_bfloat16* hbuf = (__hip_bfloat16*)(ws + off); off += (size_t)2 * NB * NH * 2;
  int* flags = (int*)(ws + off); off += (size_t)4 * 64 * FSTRIDE * 4;
  off = (off + 255) & ~(size_t)255;
  float* gi_buf = (float*)(ws + off);

  long long avail = (long long)ws_size - (long long)off;
  int TC = 256;
  while (TC > 2 && (long long)TC * NB * N3H * 4 > avail) TC >>= 1;

  {
    size_t n = (size_t)NL * N3H * NH;
    conv_w_kernel<<<dim3((n + 255) / 256), dim3(256), 0, stream>>>(
        w_ih, w_hh, wih_b, whh_hi, whh_lo);
  }
  {
    size_t n = (size_t)NT * NB * NH;
    conv_x_kernel<<<dim3((n + 255) / 256), dim3(256), 0, stream>>>(x, seqA);
  }
  {
    size_t n = (size_t)NL * NB * NH;
    init_out_kernel<<<dim3((n + 255) / 256), dim3(256), 0, stream>>>(h0, out, flags);
  }

  const size_t bh = (size_t)NB * NH;
  const int nchunks = NT / TC;
  for (int l = 0; l < NL; ++l) {
    init_hbf_kernel<<<dim3((bh + 255) / 256), dim3(256), 0, stream>>>(
        h0 + (size_t)l * bh, hbuf);
    const __hip_bfloat16* cur = (l & 1) ? seqB : seqA;
    __hip_bfloat16* nxt = (l == NL - 1) ? (__hip_bfloat16*)nullptr
                                        : ((l & 1) ? seqA : seqB);
    const __hip_bfloat16* wih_l = wih_b + (size_t)l * N3H * NH;
    const __hip_bfloat16* whha_l = whh_hi + (size_t)l * N3H * NH;
    const __hip_bfloat16* whhb_l = whh_lo + (size_t)l * NH * NH;
    const float* bih_l = b_ih + (size_t)l * N3H;
    const float* bhh_l = b_hh + (size_t)l * N3H;
    float* hfp_l = out + (size_t)l * bh;
    for (int c = 0; c < nchunks; ++c) {
      const __hip_bfloat16* Ac = cur + (size_t)c * TC * bh;
      gemm_gi_kernel<<<dim3(TC * NB / 128, N3H / 128), dim3(256), 0, stream>>>(
          Ac, wih_l, bih_l, gi_buf);
      __hip_bfloat16* so = nxt ? nxt + (size_t)c * TC * bh : (__hip_bfloat16*)nullptr;
      gru_persist_kernel<<<dim3(256), dim3(64), 0, stream>>>(
          whha_l, whhb_l, gi_buf, bhh_l, hbuf, so, hfp_l, flags,
          l * NT + c * TC, TC);
    }
  }
}